// Round 14
// baseline (762.263 us; speedup 1.0000x reference)
//
#include <hip/hip_runtime.h>
#include <hip/hip_bf16.h>

// ---------------- constants ----------------
#define T_N    2048
#define H_N    32
#define NOPE_N 128
#define ROPE_N 64
#define VD_N   128
#define QLORA_N 1536
#define KVLORA_N 512
#define IDX_H_N 32
#define IDX_D_N 128
#define TOPK_N 512
#define HID_N  2048

typedef __attribute__((ext_vector_type(8))) short bf16x8;
typedef __attribute__((ext_vector_type(4))) float f32x4;
typedef unsigned short ushortT;
typedef unsigned char uchar;

#define SCALE_F 0.07216878364870323f  // (NOPE+ROPE)^-0.5 = 192^-0.5

static __device__ __forceinline__ ushortT f2bf(float x) {
    __hip_bfloat16 b = __float2bfloat16(x);
    return *(ushortT*)&b;
}
static __device__ __forceinline__ float bf2f(ushortT u) {
    __hip_bfloat16 b = *(__hip_bfloat16*)&u;
    return __bfloat162float(b);
}

#define GLL16(g, l) __builtin_amdgcn_global_load_lds( \
    (const __attribute__((address_space(1))) unsigned int*)(g), \
    (__attribute__((address_space(3))) unsigned int*)(l), 16, 0, 0)

// exact RNE float -> e4m3fn grid
static __device__ __forceinline__ float q_e4m3(float x) {
    float ax = fabsf(x);
    unsigned b = __float_as_uint(ax);
    int e = (int)(b >> 23) - 126;
    int ue = (e - 4 > -9) ? (e - 4) : -9;
    float ulp = __int_as_float((ue + 127) << 23);
    float q = rintf(ax / ulp) * ulp;
    return copysignf(q, x);
}

// encode a value ALREADY on the e4m3fn grid (|q|<=448) to its fp8 byte
static __device__ __forceinline__ uchar enc_e4m3(float q) {
    unsigned b = __float_as_uint(q);
    unsigned s = (b >> 31) << 7;
    float ax = fabsf(q);
    if (ax == 0.f) return (uchar)s;
    int e = (int)((b >> 23) & 255) - 127;   // q = 1.m * 2^e
    if (e >= -6) {
        unsigned m = (b >> 20) & 7;         // exact: grid value has 3 mantissa bits
        return (uchar)(s | ((unsigned)(e + 7) << 3) | m);
    }
    unsigned M = (unsigned)rintf(ax * 512.f);  // subnormal: M * 2^-9, M in 1..7
    return (uchar)(s | M);
}

// ---------------- rope tables ----------------
__global__ void k_rope_tables(const int* __restrict__ pos, float* __restrict__ cosT,
                              float* __restrict__ sinT) {
    int t = blockIdx.x, i = threadIdx.x;
    double inv = 1.0 / pow(10000.0, (double)i / 32.0);
    double ang = (double)pos[t] * inv;
    cosT[t * 32 + i] = (float)cos(ang);
    sinT[t * 32 + i] = (float)sin(ang);
}

// ---------------- generic 128x128 f32 GEMM (BK=8), batched/split-K via blockIdx.z -------
template <bool BT>
__global__ __launch_bounds__(256) void gemm128(
    const float* __restrict__ A, const float* __restrict__ B, float* __restrict__ C,
    int M, int N, int K, int lda, int ldb, int ldc,
    long batchOffA, long batchOffB, long batchOffC) {
    const float* Ab = A + (size_t)batchOffA * blockIdx.z;
    const float* Bb = B + (size_t)batchOffB * blockIdx.z;
    int bm = blockIdx.y * 128, bn = blockIdx.x * 128;
    int tid = threadIdx.x;
    __shared__ float As[8][128];
    __shared__ float Bs[8][128];
    float acc[8][8];
#pragma unroll
    for (int i = 0; i < 8; ++i)
#pragma unroll
        for (int j = 0; j < 8; ++j) acc[i][j] = 0.f;
    int tx = tid & 15, ty = tid >> 4;
    int ar = tid >> 1, ak = (tid & 1) * 4;
    for (int k0 = 0; k0 < K; k0 += 8) {
        float4 av = *(const float4*)(Ab + (size_t)(bm + ar) * lda + k0 + ak);
        As[ak + 0][ar] = av.x; As[ak + 1][ar] = av.y;
        As[ak + 2][ar] = av.z; As[ak + 3][ar] = av.w;
        if (BT) {
            int n = tid >> 1, kk = (tid & 1) * 4;
            float4 bv = *(const float4*)(Bb + (size_t)(bn + n) * ldb + k0 + kk);
            Bs[kk + 0][n] = bv.x; Bs[kk + 1][n] = bv.y;
            Bs[kk + 2][n] = bv.z; Bs[kk + 3][n] = bv.w;
        } else {
            int kk = tid >> 5, n = (tid & 31) * 4;
            float4 bv = *(const float4*)(Bb + (size_t)(k0 + kk) * ldb + bn + n);
            Bs[kk][n + 0] = bv.x; Bs[kk][n + 1] = bv.y;
            Bs[kk][n + 2] = bv.z; Bs[kk][n + 3] = bv.w;
        }
        __syncthreads();
#pragma unroll
        for (int kk = 0; kk < 8; ++kk) {
            float4 a0 = *(const float4*)(&As[kk][ty * 8]);
            float4 a1 = *(const float4*)(&As[kk][ty * 8 + 4]);
            float4 b0 = *(const float4*)(&Bs[kk][tx * 8]);
            float4 b1 = *(const float4*)(&Bs[kk][tx * 8 + 4]);
            float a[8] = {a0.x, a0.y, a0.z, a0.w, a1.x, a1.y, a1.z, a1.w};
            float b[8] = {b0.x, b0.y, b0.z, b0.w, b1.x, b1.y, b1.z, b1.w};
#pragma unroll
            for (int i = 0; i < 8; ++i)
#pragma unroll
                for (int j = 0; j < 8; ++j) acc[i][j] = fmaf(a[i], b[j], acc[i][j]);
        }
        __syncthreads();
    }
    size_t cbase = (size_t)batchOffC * blockIdx.z;
#pragma unroll
    for (int i = 0; i < 8; ++i) {
        size_t r = bm + ty * 8 + i;
#pragma unroll
        for (int j = 0; j < 8; ++j) {
            size_t c = bn + tx * 8 + j;
            C[cbase + r * (size_t)ldc + c] = acc[i][j];
        }
    }
}

// ======== bf16 NT MFMA GEMM (round 14: m97 structure) ===================================
// BK=32, double-buffered LDS, global_load_lds width-16 staging with linear LDS dest +
// inverse-swizzled global source (involution l = p ^ (((p>>6)&3)<<4), 64B rows).
// CB16 epilogue: LDS bounce -> full-64B-line coalesced uint4 stores.
template <bool CB16>
__global__ __launch_bounds__(256) void bgemm(
    const ushortT* __restrict__ A, const ushortT* __restrict__ B, void* __restrict__ Cv,
    int K, int lda, int ldb, int ldc,
    long boffA, long boffB, long boffC, float scaleC) {
    const ushortT* Ab = A + (size_t)boffA * blockIdx.z;
    const ushortT* Bb = B + (size_t)boffB * blockIdx.z;
    int bm = blockIdx.y * 128, bn = blockIdx.x * 128;
    int tid = threadIdx.x, lane = tid & 63, w = tid >> 6;
    int wr = w >> 1, wc = w & 1;
    int lr = lane & 15, lk = lane >> 4;

    // 32KB: A dbuf = sbuf[0..8191] (ushorts), B dbuf = sbuf[8192..16383]
    __shared__ __align__(16) ushortT sbuf[16384];

    // staging sources (pre-swizzled global addresses; LDS dest stays linear)
    const ushortT* gA[2];
    const ushortT* gB[2];
    unsigned ubase[2];   // wave-uniform ushort index within one 8KB buffer
#pragma unroll
    for (int c = 0; c < 2; ++c) {
        int p = w * 2048 + c * 1024 + (lane << 4);     // physical byte in 8KB buffer
        int l = p ^ (((p >> 6) & 3) << 4);             // logical byte (involution)
        int row = l >> 6, e8 = (l & 63) >> 4;
        gA[c] = Ab + (size_t)(bm + row) * lda + e8 * 8;
        gB[c] = Bb + (size_t)(bn + row) * ldb + e8 * 8;
        ubase[c] = (unsigned)(w * 1024 + c * 512);     // ushort index (uniform part)
    }

    f32x4 acc[4][4];
#pragma unroll
    for (int i = 0; i < 4; ++i)
#pragma unroll
        for (int j = 0; j < 4; ++j) acc[i][j] = (f32x4){0.f, 0.f, 0.f, 0.f};

    int nk = K >> 5;
    int cur = 0;
    // prologue: stage tile 0 into buffer 0
#pragma unroll
    for (int c = 0; c < 2; ++c) {
        GLL16(gA[c], &sbuf[ubase[c]]);
        GLL16(gB[c], &sbuf[8192 + ubase[c]]);
    }
    for (int kt = 0; kt < nk; ++kt) {
        __syncthreads();   // drains vmcnt (stage of buf[cur] done) + prior lgkm
        if (kt + 1 < nk) {
            int ko = (kt + 1) << 5;
            int nb = (cur ^ 1) * 4096;
#pragma unroll
            for (int c = 0; c < 2; ++c) {
                GLL16(gA[c] + ko, &sbuf[nb + ubase[c]]);
                GLL16(gB[c] + ko, &sbuf[8192 + nb + ubase[c]]);
            }
        }
        int abase = cur * 8192;            // byte offset of A buffer
        int bbase = 16384 + cur * 8192;    // byte offset of B buffer
        bf16x8 af[4], bfr[4];
#pragma unroll
        for (int i = 0; i < 4; ++i) {
            int arow = wr * 64 + i * 16 + lr;
            af[i] = *(const bf16x8*)((const char*)sbuf + abase +
                     ((arow * 64 + lk * 16) ^ ((arow & 3) << 4)));
            int brow = wc * 64 + i * 16 + lr;
            bfr[i] = *(const bf16x8*)((const char*)sbuf + bbase +
                     ((brow * 64 + lk * 16) ^ ((brow & 3) << 4)));
        }
#pragma unroll
        for (int i = 0; i < 4; ++i)
#pragma unroll
            for (int j = 0; j < 4; ++j)
                acc[i][j] = __builtin_amdgcn_mfma_f32_16x16x32_bf16(af[i], bfr[j], acc[i][j], 0, 0, 0);
        cur ^= 1;
    }
    size_t cbase = (size_t)boffC * blockIdx.z;
    if (CB16) {
        __syncthreads();   // all waves done with sbuf
#pragma unroll
        for (int mi = 0; mi < 4; ++mi)
#pragma unroll
            for (int ni = 0; ni < 4; ++ni)
#pragma unroll
                for (int r = 0; r < 4; ++r) {
                    int row = wr * 64 + mi * 16 + lk * 4 + r;
                    int col = wc * 64 + ni * 16 + lr;
                    int off = (row * 256 + col * 2) ^ ((row & 7) << 4);
                    *(ushortT*)((char*)sbuf + off) = f2bf(acc[mi][ni][r] * scaleC);
                }
        __syncthreads();
        ushortT* outp = (ushortT*)Cv;
#pragma unroll
        for (int i = 0; i < 8; ++i) {
            int idx = i * 256 + tid;
            int row = idx >> 4, seg = idx & 15;
            uint4 v = *(const uint4*)((const char*)sbuf +
                       ((row * 256 + seg * 16) ^ ((row & 7) << 4)));
            *(uint4*)(outp + cbase + (size_t)(bm + row) * ldc + bn + seg * 8) = v;
        }
    } else {
#pragma unroll
        for (int mi = 0; mi < 4; ++mi)
#pragma unroll
            for (int ni = 0; ni < 4; ++ni) {
                int col = bn + wc * 64 + ni * 16 + lr;
#pragma unroll
                for (int r = 0; r < 4; ++r) {
                    int row = bm + wr * 64 + mi * 16 + lk * 4 + r;
                    ((float*)Cv)[cbase + (size_t)row * ldc + col] = acc[mi][ni][r];
                }
            }
    }
}

// ---------------- cast / transpose helpers ----------------
__global__ __launch_bounds__(256) void k_cast4(const float* __restrict__ src,
                                               ushortT* __restrict__ dst, int n4) {
    int i = blockIdx.x * 256 + threadIdx.x;
    if (i < n4) {
        float4 v = ((const float4*)src)[i];
        ushortT o[4] = {f2bf(v.x), f2bf(v.y), f2bf(v.z), f2bf(v.w)};
        *(uint2*)(dst + (size_t)i * 4) = *(uint2*)o;
    }
}

// dst[z][b][a] bf16 = src[a*sa + b + soff + z*sz]  (sb==1), tiles 32x32
__global__ __launch_bounds__(256) void k_tcast(const float* __restrict__ src,
                                               ushortT* __restrict__ dst,
                                               long sa, long soff, long sz,
                                               long da, long dz) {
    __shared__ float tile[32][33];
    int a0 = blockIdx.x * 32, b0 = blockIdx.y * 32;
    int tx = threadIdx.x & 31, ty = threadIdx.x >> 5;
    const float* s = src + (size_t)sz * blockIdx.z + soff;
#pragma unroll
    for (int i = ty; i < 32; i += 8)
        tile[i][tx] = s[(size_t)(a0 + i) * sa + (b0 + tx)];
    __syncthreads();
    ushortT* d = dst + (size_t)dz * blockIdx.z;
#pragma unroll
    for (int i = ty; i < 32; i += 8)
        d[(size_t)(b0 + i) * da + a0 + tx] = f2bf(tile[tx][i]);
}

// wuk_t[h][r][n] = W_kvb[r][h][n]
__global__ __launch_bounds__(256) void k_wuk_cast(const float* __restrict__ wkvb,
                                                  ushortT* __restrict__ wuk) {
    int i = blockIdx.x * 256 + threadIdx.x;
    int n = i & 127, r = (i >> 7) & 511, h = i >> 16;
    wuk[i] = f2bf(wkvb[(size_t)r * 8192 + h * 256 + n]);
}

// ------- kv postprocess -> kcat bf16 (T,576) ----
__global__ __launch_bounds__(256) void k_kv_post2(const float* __restrict__ kv,
                                                  const float* __restrict__ lnw,
                                                  const float* __restrict__ cosT,
                                                  const float* __restrict__ sinT,
                                                  ushortT* __restrict__ kcat) {
    int t = blockIdx.x, tid = threadIdx.x;
    const float* row = kv + (size_t)t * 576;
    float v0 = row[tid], v1 = row[tid + 256];
    float s = v0 * v0 + v1 * v1;
    for (int o = 32; o > 0; o >>= 1) s += __shfl_down(s, o);
    __shared__ float sm[4];
    if ((tid & 63) == 0) sm[tid >> 6] = s;
    __syncthreads();
    float tot = sm[0] + sm[1] + sm[2] + sm[3];
    float inv = 1.f / sqrtf(tot / 512.f + 1e-6f);
    ushortT* out = kcat + (size_t)t * 576;
    out[tid] = f2bf(v0 * inv * lnw[tid]);
    out[tid + 256] = f2bf(v1 * inv * lnw[tid + 256]);
    if (tid < 32) {
        float c = cosT[t * 32 + tid], sn = sinT[t * 32 + tid];
        float x1 = row[512 + 2 * tid], x2 = row[512 + 2 * tid + 1];
        out[512 + 2 * tid] = f2bf(x1 * c - x2 * sn);
        out[512 + 2 * tid + 1] = f2bf(x2 * c + x1 * sn);
    }
}

// ------- rope on q_pe (bf16 qfull) -> qcat[...,512:576] (SCALE folded) ------------------
__global__ __launch_bounds__(256) void k_rope_q2(const ushortT* __restrict__ qfull,
                                                 const float* __restrict__ cosT,
                                                 const float* __restrict__ sinT,
                                                 ushortT* __restrict__ qcat) {
    int b = blockIdx.x * 8 + (threadIdx.x >> 5);
    int i = threadIdx.x & 31;
    int t = b >> 5, h = b & 31;
    const ushortT* p = qfull + (size_t)b * 192 + 128;
    float c = cosT[t * 32 + i], s = sinT[t * 32 + i];
    float x1 = bf2f(p[2 * i]), x2 = bf2f(p[2 * i + 1]);
    ushortT* q = qcat + (size_t)t * 18432 + h * 576 + 512;
    q[2 * i] = f2bf((x1 * c - x2 * s) * SCALE_F);
    q[2 * i + 1] = f2bf((x2 * c + x1 * s) * SCALE_F);
}

// ---- indexer k: sum 16 split-K partials + layernorm + neox rope + fp8 quant -> bytes ----
__global__ __launch_bounds__(128) void k_ki_post16(const float* __restrict__ kp,
                                                   const float* __restrict__ g,
                                                   const float* __restrict__ be,
                                                   const float* __restrict__ cosT,
                                                   const float* __restrict__ sinT,
                                                   uchar* __restrict__ ki8,
                                                   float* __restrict__ kscale) {
    int t = blockIdx.x, i = threadIdx.x;
    float x = 0.f;
#pragma unroll
    for (int z = 0; z < 16; ++z) x += kp[(size_t)z * 262144 + (size_t)t * 128 + i];
    float s = x;
    for (int o = 32; o > 0; o >>= 1) s += __shfl_down(s, o);
    __shared__ float sm[2];
    if ((i & 63) == 0) sm[i >> 6] = s;
    __syncthreads();
    float mean = (sm[0] + sm[1]) / 128.f;
    float d = x - mean;
    float s2 = d * d;
    for (int o = 32; o > 0; o >>= 1) s2 += __shfl_down(s2, o);
    __shared__ float sv[2];
    if ((i & 63) == 0) sv[i >> 6] = s2;
    __syncthreads();
    float var = (sv[0] + sv[1]) / 128.f;
    float nrm = d * (1.f / sqrtf(var + 1e-6f)) * g[i] + be[i];
    __shared__ float buf[128];
    buf[i] = nrm;
    __syncthreads();
    float out;
    if (i < 32)      out = buf[i] * cosT[t * 32 + i] - buf[i + 32] * sinT[t * 32 + i];
    else if (i < 64) out = buf[i] * cosT[t * 32 + i - 32] + buf[i - 32] * sinT[t * 32 + i - 32];
    else             out = nrm;
    float a = fabsf(out);
    for (int o = 32; o > 0; o >>= 1) a = fmaxf(a, __shfl_down(a, o));
    __shared__ float am[2];
    if ((i & 63) == 0) am[i >> 6] = a;
    __syncthreads();
    float amax = fmaxf(fmaxf(am[0], am[1]), 1e-10f);
    float scale = __int_as_float((((int)ceilf(log2f(amax / 448.f))) + 127) << 23);
    ki8[(size_t)t * 128 + i] = enc_e4m3(q_e4m3(out / scale));
    if (i == 0) kscale[t] = scale;
}

// ---- indexer q: bf16 GEMM result + neox rope + fp8 quant -> bytes -----------------------
__global__ __launch_bounds__(128) void k_qi_post_bf(const ushortT* __restrict__ qi_bf,
                                                    const float* __restrict__ cosT,
                                                    const float* __restrict__ sinT,
                                                    uchar* __restrict__ qi8,
                                                    float* __restrict__ qscale) {
    int b = blockIdx.x;
    int t = b >> 5;
    int i = threadIdx.x;
    float x = bf2f(qi_bf[(size_t)b * 128 + i]);
    __shared__ float buf[128];
    buf[i] = x;
    __syncthreads();
    float out;
    if (i < 32)      out = buf[i] * cosT[t * 32 + i] - buf[i + 32] * sinT[t * 32 + i];
    else if (i < 64) out = buf[i] * cosT[t * 32 + i - 32] + buf[i - 32] * sinT[t * 32 + i - 32];
    else             out = x;
    float a = fabsf(out);
    for (int o = 32; o > 0; o >>= 1) a = fmaxf(a, __shfl_down(a, o));
    __shared__ float am[2];
    if ((i & 63) == 0) am[i >> 6] = a;
    __syncthreads();
    float amax = fmaxf(fmaxf(am[0], am[1]), 1e-10f);
    float scale = __int_as_float((((int)ceilf(log2f(amax / 448.f))) + 127) << 23);
    qi8[(size_t)b * 128 + i] = enc_e4m3(q_e4m3(out / scale));
    if (i == 0) qscale[b] = scale;
}

// ---------------- indexer weights ----------------
__global__ __launch_bounds__(256) void k_wiw(const float* __restrict__ hs,
                                             const float* __restrict__ W_iw,
                                             const float* __restrict__ qscale,
                                             float* __restrict__ wts) {
    int t = blockIdx.x, tid = threadIdx.x;
    __shared__ float hr[2048];
    for (int i = tid; i < 2048; i += 256) hr[i] = hs[(size_t)t * 2048 + i];
    __syncthreads();
    int h = tid & 31, p = tid >> 5;
    float s = 0;
    for (int k = p * 256; k < p * 256 + 256; ++k) s = fmaf(hr[k], W_iw[(size_t)k * 32 + h], s);
    __shared__ float part[8][32];
    part[p][h] = s;
    __syncthreads();
    if (tid < 32) {
        float tot = 0;
#pragma unroll
        for (int pp = 0; pp < 8; ++pp) tot += part[pp][tid];
        const float a = (float)0.08838834764831845;   // 128^-0.5
        const float b = (float)0.1767766952966369;    // 32^-0.5
        wts[t * 32 + tid] = tot * qscale[t * 32 + tid] * a * b;
    }
}

// ======== indexer score via fp8 MFMA ====
__global__ __launch_bounds__(256) void k_score8(const uchar* __restrict__ qi8,
                                                const uchar* __restrict__ ki8,
                                                const float* __restrict__ kscale,
                                                const float* __restrict__ wts,
                                                float* __restrict__ score) {
    int b = blockIdx.x;
    int ti = (int)((sqrtf(8.f * b + 1.f) - 1.f) * 0.5f);
    while ((ti + 1) * (ti + 2) / 2 <= b) ++ti;
    while (ti * (ti + 1) / 2 > b) --ti;
    int si = b - ti * (ti + 1) / 2;
    int t0 = ti * 32, s0 = si * 32;
    int tid = threadIdx.x, lane = tid & 63, w = tid >> 6;
    int qt = w >> 1, qs = w & 1;
    int col = lane & 15, g = lane >> 4;

    __shared__ __align__(16) uchar k8s[4096];
    __shared__ __align__(16) uchar q8s[32768];
    __shared__ float wts_s[32][33];

    {
        int row = tid >> 3, inner = tid & 7;
        uint4 v = *(const uint4*)(ki8 + (size_t)(s0 + row) * 128 + inner * 16);
        *(uint4*)(k8s + ((row * 128 + inner * 16) ^ ((row & 7) << 4))) = v;
    }
    for (int c = tid; c < 1024; c += 256) {
        int tl = c >> 5, h = c & 31;
        wts_s[tl][h] = wts[(size_t)(t0 + tl) * 32 + h];
    }

    float ksc = kscale[s0 + qs * 16 + col];
    int arow = qt * 16 + col;
    int brow = qs * 16 + col;
    float sacc[4] = {0.f, 0.f, 0.f, 0.f};

    for (int h0 = 0; h0 < 32; h0 += 8) {
        __syncthreads();
        for (int c = tid; c < 2048; c += 256) {
            int hh = c >> 8, row = (c >> 3) & 31, inner = c & 7;
            uint4 v = *(const uint4*)(qi8 + ((size_t)(t0 + row) * 32 + h0 + hh) * 128 + inner * 16);
            *(uint4*)(q8s + hh * 4096 + ((row * 128 + inner * 16) ^ ((row & 7) << 4))) = v;
        }
        __syncthreads();
#pragma unroll
        for (int hh = 0; hh < 8; ++hh) {
            f32x4 c4 = (f32x4){0.f, 0.f, 0.f, 0.f};
#pragma unroll
            for (int kk = 0; kk < 4; ++kk) {
                long long a = *(const long long*)(q8s + hh * 4096 +
                              ((arow * 128 + kk * 32 + g * 8) ^ ((arow & 7) << 4)));
                long long bb = *(const long long*)(k8s +
                              ((brow * 128 + kk * 32 + g * 8) ^ ((brow & 7) << 4)));
                c4 = __builtin_amdgcn_mfma_f32_16x16x32_fp8_fp8(a, bb, c4, 0, 0, 0);
            }
            int h = h0 + hh;
#pragma unroll
            for (int r = 0; r < 4; ++r)
                sacc[r] = fmaf(fmaxf(c4[r] * ksc, 0.f), wts_s[qt * 16 + g * 4 + r][h], sacc[r]);
        }
    }
    int t = t0 + qt * 16 + g * 4;
    int s = s0 + qs * 16 + col;
#pragma unroll
    for (int r = 0; r < 4; ++r)
        if (s <= t + r) score[(size_t)(t + r) * T_N + s] = sacc[r];
}

// ---------------- top-512 per row (stable ties) --------------------------
__global__ __launch_bounds__(256) void k_topk(const float* __restrict__ score,
                                              int* __restrict__ tki, int* __restrict__ tkc) {
    int t = blockIdx.x;
    int n = t + 1;
    int tid = threadIdx.x;
    if (n <= TOPK_N) {
        for (int i = tid; i < n; i += 256) tki[(size_t)t * TOPK_N + i] = i;
        if (tid == 0) tkc[t] = n;
        return;
    }
    __shared__ unsigned keys[2048];
    const float* row = score + (size_t)t * T_N;
    for (int i = tid; i < n; i += 256) {
        float f = row[i] + 0.f;
        unsigned u = __float_as_uint(f);
        u = (u & 0x80000000u) ? ~u : (u | 0x80000000u);
        keys[i] = u;
    }
    __shared__ int hist[256];
    __shared__ unsigned sh_prefix;
    __shared__ int sh_need;
    if (tid == 0) { sh_prefix = 0u; sh_need = TOPK_N; }
    __syncthreads();
    unsigned maskHi = 0;
    for (int level = 3; level >= 0; --level) {
        hist[tid] = 0;
        __syncthreads();
        unsigned prefix = sh_prefix;
        int shift = level * 8;
        for (int i = tid; i < n; i += 256) {
            unsigned kk = keys[i];
            if ((kk & maskHi) == prefix) atomicAdd(&hist[(kk >> shift) & 255], 1);
        }
        __syncthreads();
        if (tid == 0) {
            int need = sh_need, cum = 0, bsel = 255;
            for (int bb = 255; bb >= 0; --bb) {
                if (cum + hist[bb] >= need) { bsel = bb; break; }
                cum += hist[bb];
            }
            sh_need = need - cum;
            sh_prefix = prefix | ((unsigned)bsel << shift);
        }
        __syncthreads();
        maskHi |= (0xFFu << shift);
    }
    unsigned thr = sh_prefix;
    int needEq = sh_need;
    int base = tid * 8;
    int eqcnt = 0;
#pragma unroll
    for (int j = 0; j < 8; ++j) {
        int i = base + j;
        if (i < n && keys[i] == thr) eqcnt++;
    }
    __shared__ int scn[256];
    scn[tid] = eqcnt;
    __syncthreads();
    for (int off = 1; off < 256; off <<= 1) {
        int add = (tid >= off) ? scn[tid - off] : 0;
        __syncthreads();
        scn[tid] += add;
        __syncthreads();
    }
    int eq_excl = scn[tid] - eqcnt;
    int acnt = 0;
    {
        int eqr = eq_excl;
#pragma unroll
        for (int j = 0; j < 8; ++j) {
            int i = base + j;
            if (i < n) {
                unsigned kk = keys[i];
                bool a = (kk > thr) || (kk == thr && eqr < needEq);
                if (kk == thr) eqr++;
                if (a) acnt++;
            }
        }
    }
    __syncthreads();
    scn[tid] = acnt;
    __syncthreads();
    for (int off = 1; off < 256; off <<= 1) {
        int add = (tid >= off) ? scn[tid - off] : 0;
        __syncthreads();
        scn[tid] += add;
        __syncthreads();
    }
    int pos = scn[tid] - acnt;
    {
        int eqr = eq_excl;
#pragma unroll
        for (int j = 0; j < 8; ++j) {
            int i = base + j;
            if (i < n) {
                unsigned kk = keys[i];
                bool a = (kk > thr) || (kk == thr && eqr < needEq);
                if (kk == thr) eqr++;
                if (a) tki[(size_t)t * TOPK_N + (pos++)] = i;
            }
        }
    }
    if (tid == 0) tkc[t] = TOPK_N;
}

// ======== fused sparse MFMA attention, single-pass flash-style (round 14) ===============
// Change vs r13: kbV gains a part-bit-2 -> addr-bit-6 XOR on write (^((part&4)<<4)) and
// the matching dim-derived XOR on read (part == (dim>>3)&7), spreading the V-transpose
// writes across all 32 banks (same-dword pairs only).
__global__ __launch_bounds__(256, 2) void k_attn_mfma(const ushortT* __restrict__ qcat,
                                                      const ushortT* __restrict__ kcat,
                                                      const int* __restrict__ tki,
                                                      const int* __restrict__ tkc,
                                                      ushortT* __restrict__ olat) {
    int t = blockIdx.x;
    int tid = threadIdx.x;
    int lane = tid & 63;
    int w = tid >> 6;                 // 4 waves
    int S = tkc[t];
    int nchunk = (S + 31) >> 5;

    __shared__ int idx_s[512];
    __shared__ __align__(16) ushortT kbK[18 * 1024];  // [kk][32 keys][32 dims] 36864B
    __shared__ __align__(16) ushortT kbV[512 * 32];   // [512 dims][32 keys, rotated]
    __shared__ __align__(16) ushortT psc[32 * 32];    // [32 heads][32 keys]     2048B
    __shared__ float red[64];                         // [head][nt] partial sums

    idx_s[tid] = (tid < S) ? tki[(size_t)t * TOPK_N + tid] : 0;
    idx_s[tid + 256] = (tid + 256 < S) ? tki[(size_t)t * TOPK_N + tid + 256] : 0;

    int lr = lane & 15, lk = lane >> 4;
    int mt = w >> 1, nt = w & 1;      // score quadrant: heads mt*16, keys nt*16

    bf16x8 qf[18];
    {
        const ushortT* qrow = qcat + (size_t)t * 18432 + (size_t)(mt * 16 + lr) * 576 + lk * 8;
#pragma unroll
        for (int kk = 0; kk < 18; ++kk) qf[kk] = *(const bf16x8*)(qrow + kk * 32);
    }
    __syncthreads();

    // coalesced staging map: 8 lanes cover 128 consecutive bytes of one key row
    int skey = (w << 3) | (lane >> 3);   // 0..31
    int part = lane & 7;                 // 16B chunk index within each 128B group

    f32x4 oa[2][8];
#pragma unroll
    for (int i = 0; i < 2; ++i)
#pragma unroll
        for (int j = 0; j < 8; ++j) oa[i][j] = (f32x4){0.f, 0.f, 0.f, 0.f};
    float sm_[4] = {0.f, 0.f, 0.f, 0.f};

    uint4 sv[9];
    {   // prefetch chunk 0
        bool ok = skey < S;
        const ushortT* g = kcat + (size_t)idx_s[skey] * 576 + part * 8;
#pragma unroll
        for (int i = 0; i < 9; ++i) {
            uint4 v = {0, 0, 0, 0};
            if (ok) v = *(const uint4*)(g + i * 64);
            sv[i] = v;
        }
    }

    for (int p = 0; p < nchunk; ++p) {
        // ---- stage chunk p: K-layout + V-transposed (rotated + bit6 spread) ----
#pragma unroll
        for (int i = 0; i < 9; ++i) {
            int dg = part + i * 8;
            int off = ((skey * 64 + (dg & 3) * 16) ^ ((skey & 7) << 4)) + (dg >> 2) * 2048;
            *(uint4*)((char*)kbK + off) = sv[i];
        }
#pragma unroll
        for (int i = 0; i < 8; ++i) {           // dg < 64: V dims only
            int dg = part + i * 8;
            int inner = ((((skey >> 3) + (dg & 3)) & 3) << 4) | ((skey & 7) << 1);
            const ushortT* pv = (const ushortT*)&sv[i];
#pragma unroll
            for (int j = 0; j < 8; ++j) {       // dim = dg*8+j, dim&7 == j
                int off = ((dg * 8 + j) * 64 + inner) ^ (j << 4) ^ ((part & 4) << 4);
                *(ushortT*)((char*)kbV + off) = pv[j];
            }
        }
        __syncthreads();
        // issue prefetch AFTER the barrier: latency hides under score MFMA + exp
        if (p + 1 < nchunk) {
            int gk = (p + 1) * 32 + skey;
            bool ok = gk < S;
            const ushortT* g = kcat + (size_t)idx_s[gk] * 576 + part * 8;
#pragma unroll
            for (int i = 0; i < 9; ++i) {
                uint4 v = {0, 0, 0, 0};
                if (ok) v = *(const uint4*)(g + i * 64);
                sv[i] = v;
            }
        }
        // ---- score: C[16h][16k] for quadrant (mt, nt) ----
        f32x4 acc = (f32x4){0.f, 0.f, 0.f, 0.f};
        int brow = nt * 16 + lr;
#pragma unroll
        for (int kk = 0; kk < 18; ++kk) {
            bf16x8 b = *(const bf16x8*)((const char*)kbK + kk * 2048 +
                        ((brow * 64 + lk * 16) ^ ((brow & 7) << 4)));
            acc = __builtin_amdgcn_mfma_f32_16x16x32_bf16(qf[kk], b, acc, 0, 0, 0);
        }
        // ---- exp (m=0), accumulate sums, write P chunk ----
        int key_g = p * 32 + nt * 16 + lr;
        int hb = mt * 16 + lk * 4;
#pragma unroll
        for (int r = 0; r < 4; ++r) {
            float e = (key_g < S) ? expf(acc[r]) : 0.f;
            sm_[r] += e;
            int head = hb + r;
            int off = (head * 64 + (nt * 16 + lr) * 2) ^ ((head & 7) << 4);
            *(ushortT*)((char*)psc + off) = f2bf(e);
        }
        __syncthreads();
        // ---- PV: all 32 heads x this wave's 128 dims, K = 32 chunk keys ----
#pragma unroll
        for (int m2 = 0; m2 < 2; ++m2) {
            int arow = m2 * 16 + lr;
            bf16x8 a = *(const bf16x8*)((const char*)psc +
                        ((arow * 64 + lk * 16) ^ ((arow & 7) << 4)));
#pragma unroll
            for (int n2 = 0; n2 < 8; ++n2) {
                int dim = w * 128 + n2 * 16 + lr;
                int grp = (lk + ((dim >> 3) & 3)) & 3;
                bf16x8 b = *(const bf16x8*)((const char*)kbV +
                            ((dim * 64 + (grp << 4)) ^ ((dim & 7) << 4) ^ (((dim >> 3) & 4) << 4)));
                oa[m2][n2] = __builtin_amdgcn_mfma_f32_16x16x32_bf16(a, b, oa[m2][n2], 0, 0, 0);
            }
        }
        __syncthreads();
    }
    // ---- reduce per-head sums: over lr lanes, then across nt waves via LDS ----
#pragma unroll
    for (int off = 1; off < 16; off <<= 1)
#pragma unroll
        for (int r = 0; r < 4; ++r) sm_[r] += __shfl_xor(sm_[r], off);
    if (lr == 0) {
#pragma unroll
        for (int r = 0; r < 4; ++r) red[(mt * 16 + lk * 4 + r) * 2 + nt] = sm_[r];
    }
    __syncthreads();
    // ---- normalize, stage [32 heads][512 dims] bf16 into kbK (swizzled) ----
#pragma unroll
    for (int m2 = 0; m2 < 2; ++m2)
#pragma unroll
        for (int r = 0; r < 4; ++r) {
            int head = m2 * 16 + lk * 4 + r;
            float dvv = 1.f / (red[head * 2] + red[head * 2 + 1]);
#pragma unroll
            for (int n2 = 0; n2 < 8; ++n2) {
                int dim = w * 128 + n2 * 16 + lr;
                int off = (head * 1024 + dim * 2) ^ ((head & 7) << 4);
                *(ushortT*)((char*)kbK + off) = f2bf(oa[m2][n2][r] * dvv);
            }
        }
    __syncthreads();
    // ---- coalesced store: 4 consecutive lanes cover 64B of one head row ----
    ushortT* orow = olat + (size_t)t * 18432;
#pragma unroll
    for (int i = 0; i < 8; ++i) {
        int idx = i * 256 + tid;
        int head = idx >> 6, seg = idx & 63;
        uint4 v = *(const uint4*)((const char*)kbK +
                   ((head * 1024 + seg * 16) ^ ((head & 7) << 4)));
        *(uint4*)(orow + head * 512 + seg * 8) = v;
    }
}

// ---------------- launch ----------------
extern "C" void kernel_launch(void* const* d_in, const int* in_sizes, int n_in,
                              void* d_out, int out_size, void* d_ws, size_t ws_size,
                              hipStream_t stream) {
    (void)in_sizes; (void)n_in; (void)out_size; (void)ws_size;
    const int*   positions = (const int*)d_in[0];
    const float* hs        = (const float*)d_in[1];
    const float* q_c       = (const float*)d_in[2];
    const float* kv_lora   = (const float*)d_in[3];
    const float* W_qb      = (const float*)d_in[4];
    const float* W_kvb     = (const float*)d_in[5];
    const float* W_o       = (const float*)d_in[6];
    const float* kv_ln     = (const float*)d_in[7];
    const float* W_iq      = (const float*)d_in[8];
    const float* W_ik      = (const float*)d_in[9];
    const float* gamma     = (const float*)d_in[10];
    const float* beta      = (const float*)d_in[11];
    const float* W_iw      = (const float*)d_in[12];

    float* ws = (float*)d_ws;
    // workspace (float offsets); high-water 50,204,672 fl = 200.8 MB (< 218.4 proven)
    float*   cosT   = ws;                          // 65,536
    float*   sinT   = ws + 65536;                  // 65,536
    int*     tki    = (int*)(ws + 131072);         // 1,048,576
    int*     tkc    = (int*)(ws + 1179648);        // 2,048
    ushortT* kcat   = (ushortT*)(ws + 1181696);    // 589,824 fl
    float*   kscale = ws + 1771520;                // 2,048
    float*   qscale = ws + 1773568;                // 65,536
    float*   wts    = ws + 1839104;                // 65,536
    uchar*   qi8    = (uchar*)(ws + 1904640);      // 2,097,152 fl (8 MB bytes)
    uchar*   ki8    = (uchar*)(ws + 4001792);      // 65,536 fl
    // qc_bf persistent through step 11:
    ushortT* qc_bf  = (ushortT*)(ws + 4067328);    // 1,572,864 fl [2a -> read 4, 11]
    // REGION R1 5,640,192..20,844,544, time-multiplexed:
    ushortT* wiq_t  = (ushortT*)(ws + 5640192);    // 3,145,728 fl [2b -> dead after 4]
    float*   kip    = ws + 8785920;                // 4,194,304  [2 -> dead after 3]
    ushortT* qi_bf  = (ushortT*)(ws + 12980224);   // 4,194,304 fl [4 -> dead after 5]
    ushortT* wqb_t  = (ushortT*)(ws + 5640192);    // 4,718,592 fl [10, over wiq_t/kip]
    ushortT* wuk_t  = (ushortT*)(ws + 10358784);   // 1,048,576 fl [10 -> dead after 13]
    ushortT* wuv_t  = (ushortT*)(ws + 11407360);   // 1,048,576 fl [10 -> read at 15]
    ushortT* wo_t   = (ushortT*)(ws + 12980224);   // 4,194,304 fl [10, over qi_bf]
    // score / vbuf slot:
    float*   score  = ws + 20844544;               // 4,194,304 [7 -> dead after 8]
    ushortT* vbuf   = (ushortT*)(ws + 20844544);   // 4,194,304 fl [15 -> 16]
    // persistent tail:
    ushortT* qfull_bf = (ushortT*)(ws + 25038848); // 6,291,456 fl [11 -> 12,13]
    ushortT* qcat   = (ushortT*)(ws + 31330304);   // 18,874,368 fl; o written in place (14)

    // 1. rope tables
    k_rope_tables<<<T_N, 32, 0, stream>>>(positions, cosT, sinT);
    // 2a/2b. bf16 casts for the q-path GEMMs
    k_cast4<<<3072, 256, 0, stream>>>(q_c, qc_bf, T_N * QLORA_N / 4);
    k_tcast<<<dim3(48, 128, 1), 256, 0, stream>>>(W_iq, wiq_t, 4096, 0, 0, 1536, 0);
    // 2. indexer k: hs @ W_ik (2048x128x2048), split-K x16 -> partials (f32, exact)
    gemm128<false><<<dim3(1, 16, 16), 256, 0, stream>>>(
        hs, W_ik, kip, T_N, 128, 128, HID_N, 128, 128, 128, 16384, 262144);
    // 3. sum partials + LN + neox rope + fp8 quant -> ki8 bytes
    k_ki_post16<<<T_N, 128, 0, stream>>>(kip, gamma, beta, cosT, sinT, ki8, kscale);
    // 4. indexer q: qc_bf @ wiq_t (bf16 MFMA) -> qi_bf (2048x4096)
    bgemm<true><<<dim3(32, 16, 1), 256, 0, stream>>>(
        qc_bf, wiq_t, qi_bf, QLORA_N, QLORA_N, QLORA_N, 4096, 0, 0, 0, 1.f);
    // 5. neox rope + fp8 quant -> qi8 bytes
    k_qi_post_bf<<<T_N * IDX_H_N, 128, 0, stream>>>(qi_bf, cosT, sinT, qi8, qscale);
    // 6. indexer weights
    k_wiw<<<T_N, 256, 0, stream>>>(hs, W_iw, qscale, wts);
    // 7. indexer score via fp8 MFMA
    k_score8<<<2080, 256, 0, stream>>>(qi8, ki8, kscale, wts, score);
    // 8. top-512
    k_topk<<<T_N, 256, 0, stream>>>(score, tki, tkc);
    // 9. kv rms_norm + k_pe rope -> kcat bf16
    k_kv_post2<<<T_N, 256, 0, stream>>>(kv_lora, kv_ln, cosT, sinT, kcat);
    // 10. remaining weight transposes (R1 free again)
    k_tcast<<<dim3(48, 192, 1), 256, 0, stream>>>(W_qb, wqb_t, 6144, 0, 0, 1536, 0);
    k_wuk_cast<<<8192, 256, 0, stream>>>(W_kvb, wuk_t);
    k_tcast<<<dim3(16, 4, 32), 256, 0, stream>>>(W_kvb, wuv_t, 8192, 128, 256, 512, 65536);
    k_tcast<<<dim3(128, 64, 1), 256, 0, stream>>>(W_o, wo_t, 2048, 0, 0, 4096, 0);
    // 11. qfull = q_c @ W_qb (bf16 MFMA) -> bf16 (T,32,192)
    bgemm<true><<<dim3(48, 16, 1), 256, 0, stream>>>(
        qc_bf, wqb_t, qfull_bf, QLORA_N, QLORA_N, QLORA_N, 6144, 0, 0, 0, 1.f);
    // 12. rope q_pe -> qcat[...,512:576]
    k_rope_q2<<<T_N * H_N / 8, 256, 0, stream>>>(qfull_bf, cosT, sinT, qcat);
    // 13. q_lat = q_nope @ W_UK^T per head -> qcat[...,0:512] (SCALE folded)
    bgemm<true><<<dim3(4, 16, 32), 256, 0, stream>>>(
        qfull_bf, wuk_t, qcat, NOPE_N, 6144, 128, 18432, 192, 65536, 576, SCALE_F);
    // 14. fused sparse MFMA attention (single-pass) -> o written in place into qcat rows
    k_attn_mfma<<<T_N, 256, 0, stream>>>(qcat, kcat, tki, tkc, qcat);
    // 15. v = o @ W_UV per head -> vbuf bf16 (T,4096)
    bgemm<true><<<dim3(1, 16, 32), 256, 0, stream>>>(
        qcat, wuv_t, vbuf, KVLORA_N, 18432, 512, 4096, 512, 65536, 128, 1.f);
    // 16. out = vbuf @ W_o -> f32
    bgemm<false><<<dim3(16, 16, 1), 256, 0, stream>>>(
        vbuf, wo_t, (float*)d_out, H_N * VD_N, 4096, 4096, HID_N, 0, 0, 0, 1.f);
}

// Round 15
// 647.646 us; speedup vs baseline: 1.1770x; 1.1770x over previous
//
#include <hip/hip_runtime.h>
#include <hip/hip_bf16.h>

// ---------------- constants ----------------
#define T_N    2048
#define H_N    32
#define NOPE_N 128
#define ROPE_N 64
#define VD_N   128
#define QLORA_N 1536
#define KVLORA_N 512
#define IDX_H_N 32
#define IDX_D_N 128
#define TOPK_N 512
#define HID_N  2048

typedef __attribute__((ext_vector_type(8))) short bf16x8;
typedef __attribute__((ext_vector_type(4))) float f32x4;
typedef unsigned short ushortT;
typedef unsigned char uchar;

#define SCALE_F 0.07216878364870323f  // (NOPE+ROPE)^-0.5 = 192^-0.5

static __device__ __forceinline__ ushortT f2bf(float x) {
    __hip_bfloat16 b = __float2bfloat16(x);
    return *(ushortT*)&b;
}
static __device__ __forceinline__ float bf2f(ushortT u) {
    __hip_bfloat16 b = *(__hip_bfloat16*)&u;
    return __bfloat162float(b);
}

#define GLL16(g, l) __builtin_amdgcn_global_load_lds( \
    (const __attribute__((address_space(1))) unsigned int*)(g), \
    (__attribute__((address_space(3))) unsigned int*)(l), 16, 0, 0)

// exact RNE float -> e4m3fn grid
static __device__ __forceinline__ float q_e4m3(float x) {
    float ax = fabsf(x);
    unsigned b = __float_as_uint(ax);
    int e = (int)(b >> 23) - 126;
    int ue = (e - 4 > -9) ? (e - 4) : -9;
    float ulp = __int_as_float((ue + 127) << 23);
    float q = rintf(ax / ulp) * ulp;
    return copysignf(q, x);
}

// encode a value ALREADY on the e4m3fn grid (|q|<=448) to its fp8 byte
static __device__ __forceinline__ uchar enc_e4m3(float q) {
    unsigned b = __float_as_uint(q);
    unsigned s = (b >> 31) << 7;
    float ax = fabsf(q);
    if (ax == 0.f) return (uchar)s;
    int e = (int)((b >> 23) & 255) - 127;   // q = 1.m * 2^e
    if (e >= -6) {
        unsigned m = (b >> 20) & 7;         // exact: grid value has 3 mantissa bits
        return (uchar)(s | ((unsigned)(e + 7) << 3) | m);
    }
    unsigned M = (unsigned)rintf(ax * 512.f);  // subnormal: M * 2^-9, M in 1..7
    return (uchar)(s | M);
}

// ---------------- rope tables ----------------
__global__ void k_rope_tables(const int* __restrict__ pos, float* __restrict__ cosT,
                              float* __restrict__ sinT) {
    int t = blockIdx.x, i = threadIdx.x;
    double inv = 1.0 / pow(10000.0, (double)i / 32.0);
    double ang = (double)pos[t] * inv;
    cosT[t * 32 + i] = (float)cos(ang);
    sinT[t * 32 + i] = (float)sin(ang);
}

// ---------------- generic 128x128 f32 GEMM (BK=8), batched/split-K via blockIdx.z -------
template <bool BT>
__global__ __launch_bounds__(256) void gemm128(
    const float* __restrict__ A, const float* __restrict__ B, float* __restrict__ C,
    int M, int N, int K, int lda, int ldb, int ldc,
    long batchOffA, long batchOffB, long batchOffC) {
    const float* Ab = A + (size_t)batchOffA * blockIdx.z;
    const float* Bb = B + (size_t)batchOffB * blockIdx.z;
    int bm = blockIdx.y * 128, bn = blockIdx.x * 128;
    int tid = threadIdx.x;
    __shared__ float As[8][128];
    __shared__ float Bs[8][128];
    float acc[8][8];
#pragma unroll
    for (int i = 0; i < 8; ++i)
#pragma unroll
        for (int j = 0; j < 8; ++j) acc[i][j] = 0.f;
    int tx = tid & 15, ty = tid >> 4;
    int ar = tid >> 1, ak = (tid & 1) * 4;
    for (int k0 = 0; k0 < K; k0 += 8) {
        float4 av = *(const float4*)(Ab + (size_t)(bm + ar) * lda + k0 + ak);
        As[ak + 0][ar] = av.x; As[ak + 1][ar] = av.y;
        As[ak + 2][ar] = av.z; As[ak + 3][ar] = av.w;
        if (BT) {
            int n = tid >> 1, kk = (tid & 1) * 4;
            float4 bv = *(const float4*)(Bb + (size_t)(bn + n) * ldb + k0 + kk);
            Bs[kk + 0][n] = bv.x; Bs[kk + 1][n] = bv.y;
            Bs[kk + 2][n] = bv.z; Bs[kk + 3][n] = bv.w;
        } else {
            int kk = tid >> 5, n = (tid & 31) * 4;
            float4 bv = *(const float4*)(Bb + (size_t)(k0 + kk) * ldb + bn + n);
            Bs[kk][n + 0] = bv.x; Bs[kk][n + 1] = bv.y;
            Bs[kk][n + 2] = bv.z; Bs[kk][n + 3] = bv.w;
        }
        __syncthreads();
#pragma unroll
        for (int kk = 0; kk < 8; ++kk) {
            float4 a0 = *(const float4*)(&As[kk][ty * 8]);
            float4 a1 = *(const float4*)(&As[kk][ty * 8 + 4]);
            float4 b0 = *(const float4*)(&Bs[kk][tx * 8]);
            float4 b1 = *(const float4*)(&Bs[kk][tx * 8 + 4]);
            float a[8] = {a0.x, a0.y, a0.z, a0.w, a1.x, a1.y, a1.z, a1.w};
            float b[8] = {b0.x, b0.y, b0.z, b0.w, b1.x, b1.y, b1.z, b1.w};
#pragma unroll
            for (int i = 0; i < 8; ++i)
#pragma unroll
                for (int j = 0; j < 8; ++j) acc[i][j] = fmaf(a[i], b[j], acc[i][j]);
        }
        __syncthreads();
    }
    size_t cbase = (size_t)batchOffC * blockIdx.z;
#pragma unroll
    for (int i = 0; i < 8; ++i) {
        size_t r = bm + ty * 8 + i;
#pragma unroll
        for (int j = 0; j < 8; ++j) {
            size_t c = bn + tx * 8 + j;
            C[cbase + r * (size_t)ldc + c] = acc[i][j];
        }
    }
}

// ======== bf16 NT MFMA GEMM (m97 structure, kept from round 14) =========================
// BK=32, double-buffered LDS, global_load_lds width-16 staging with linear LDS dest +
// inverse-swizzled global source (involution l = p ^ (((p>>6)&3)<<4), 64B rows).
// CB16 epilogue: LDS bounce -> full-64B-line coalesced uint4 stores.
template <bool CB16>
__global__ __launch_bounds__(256) void bgemm(
    const ushortT* __restrict__ A, const ushortT* __restrict__ B, void* __restrict__ Cv,
    int K, int lda, int ldb, int ldc,
    long boffA, long boffB, long boffC, float scaleC) {
    const ushortT* Ab = A + (size_t)boffA * blockIdx.z;
    const ushortT* Bb = B + (size_t)boffB * blockIdx.z;
    int bm = blockIdx.y * 128, bn = blockIdx.x * 128;
    int tid = threadIdx.x, lane = tid & 63, w = tid >> 6;
    int wr = w >> 1, wc = w & 1;
    int lr = lane & 15, lk = lane >> 4;

    // 32KB: A dbuf = sbuf[0..8191] (ushorts), B dbuf = sbuf[8192..16383]
    __shared__ __align__(16) ushortT sbuf[16384];

    // staging sources (pre-swizzled global addresses; LDS dest stays linear)
    const ushortT* gA[2];
    const ushortT* gB[2];
    unsigned ubase[2];   // wave-uniform ushort index within one 8KB buffer
#pragma unroll
    for (int c = 0; c < 2; ++c) {
        int p = w * 2048 + c * 1024 + (lane << 4);     // physical byte in 8KB buffer
        int l = p ^ (((p >> 6) & 3) << 4);             // logical byte (involution)
        int row = l >> 6, e8 = (l & 63) >> 4;
        gA[c] = Ab + (size_t)(bm + row) * lda + e8 * 8;
        gB[c] = Bb + (size_t)(bn + row) * ldb + e8 * 8;
        ubase[c] = (unsigned)(w * 1024 + c * 512);     // ushort index (uniform part)
    }

    f32x4 acc[4][4];
#pragma unroll
    for (int i = 0; i < 4; ++i)
#pragma unroll
        for (int j = 0; j < 4; ++j) acc[i][j] = (f32x4){0.f, 0.f, 0.f, 0.f};

    int nk = K >> 5;
    int cur = 0;
    // prologue: stage tile 0 into buffer 0
#pragma unroll
    for (int c = 0; c < 2; ++c) {
        GLL16(gA[c], &sbuf[ubase[c]]);
        GLL16(gB[c], &sbuf[8192 + ubase[c]]);
    }
    for (int kt = 0; kt < nk; ++kt) {
        __syncthreads();   // drains vmcnt (stage of buf[cur] done) + prior lgkm
        if (kt + 1 < nk) {
            int ko = (kt + 1) << 5;
            int nb = (cur ^ 1) * 4096;
#pragma unroll
            for (int c = 0; c < 2; ++c) {
                GLL16(gA[c] + ko, &sbuf[nb + ubase[c]]);
                GLL16(gB[c] + ko, &sbuf[8192 + nb + ubase[c]]);
            }
        }
        int abase = cur * 8192;            // byte offset of A buffer
        int bbase = 16384 + cur * 8192;    // byte offset of B buffer
        bf16x8 af[4], bfr[4];
#pragma unroll
        for (int i = 0; i < 4; ++i) {
            int arow = wr * 64 + i * 16 + lr;
            af[i] = *(const bf16x8*)((const char*)sbuf + abase +
                     ((arow * 64 + lk * 16) ^ ((arow & 3) << 4)));
            int brow = wc * 64 + i * 16 + lr;
            bfr[i] = *(const bf16x8*)((const char*)sbuf + bbase +
                     ((brow * 64 + lk * 16) ^ ((brow & 3) << 4)));
        }
#pragma unroll
        for (int i = 0; i < 4; ++i)
#pragma unroll
            for (int j = 0; j < 4; ++j)
                acc[i][j] = __builtin_amdgcn_mfma_f32_16x16x32_bf16(af[i], bfr[j], acc[i][j], 0, 0, 0);
        cur ^= 1;
    }
    size_t cbase = (size_t)boffC * blockIdx.z;
    if (CB16) {
        __syncthreads();   // all waves done with sbuf
#pragma unroll
        for (int mi = 0; mi < 4; ++mi)
#pragma unroll
            for (int ni = 0; ni < 4; ++ni)
#pragma unroll
                for (int r = 0; r < 4; ++r) {
                    int row = wr * 64 + mi * 16 + lk * 4 + r;
                    int col = wc * 64 + ni * 16 + lr;
                    int off = (row * 256 + col * 2) ^ ((row & 7) << 4);
                    *(ushortT*)((char*)sbuf + off) = f2bf(acc[mi][ni][r] * scaleC);
                }
        __syncthreads();
        ushortT* outp = (ushortT*)Cv;
#pragma unroll
        for (int i = 0; i < 8; ++i) {
            int idx = i * 256 + tid;
            int row = idx >> 4, seg = idx & 15;
            uint4 v = *(const uint4*)((const char*)sbuf +
                       ((row * 256 + seg * 16) ^ ((row & 7) << 4)));
            *(uint4*)(outp + cbase + (size_t)(bm + row) * ldc + bn + seg * 8) = v;
        }
    } else {
#pragma unroll
        for (int mi = 0; mi < 4; ++mi)
#pragma unroll
            for (int ni = 0; ni < 4; ++ni) {
                int col = bn + wc * 64 + ni * 16 + lr;
#pragma unroll
                for (int r = 0; r < 4; ++r) {
                    int row = bm + wr * 64 + mi * 16 + lk * 4 + r;
                    ((float*)Cv)[cbase + (size_t)row * ldc + col] = acc[mi][ni][r];
                }
            }
    }
}

// ---------------- cast / transpose helpers ----------------
__global__ __launch_bounds__(256) void k_cast4(const float* __restrict__ src,
                                               ushortT* __restrict__ dst, int n4) {
    int i = blockIdx.x * 256 + threadIdx.x;
    if (i < n4) {
        float4 v = ((const float4*)src)[i];
        ushortT o[4] = {f2bf(v.x), f2bf(v.y), f2bf(v.z), f2bf(v.w)};
        *(uint2*)(dst + (size_t)i * 4) = *(uint2*)o;
    }
}

// dst[z][b][a] bf16 = src[a*sa + b + soff + z*sz]  (sb==1), tiles 32x32
__global__ __launch_bounds__(256) void k_tcast(const float* __restrict__ src,
                                               ushortT* __restrict__ dst,
                                               long sa, long soff, long sz,
                                               long da, long dz) {
    __shared__ float tile[32][33];
    int a0 = blockIdx.x * 32, b0 = blockIdx.y * 32;
    int tx = threadIdx.x & 31, ty = threadIdx.x >> 5;
    const float* s = src + (size_t)sz * blockIdx.z + soff;
#pragma unroll
    for (int i = ty; i < 32; i += 8)
        tile[i][tx] = s[(size_t)(a0 + i) * sa + (b0 + tx)];
    __syncthreads();
    ushortT* d = dst + (size_t)dz * blockIdx.z;
#pragma unroll
    for (int i = ty; i < 32; i += 8)
        d[(size_t)(b0 + i) * da + a0 + tx] = f2bf(tile[tx][i]);
}

// wuk_t[h][r][n] = W_kvb[r][h][n]
__global__ __launch_bounds__(256) void k_wuk_cast(const float* __restrict__ wkvb,
                                                  ushortT* __restrict__ wuk) {
    int i = blockIdx.x * 256 + threadIdx.x;
    int n = i & 127, r = (i >> 7) & 511, h = i >> 16;
    wuk[i] = f2bf(wkvb[(size_t)r * 8192 + h * 256 + n]);
}

// ------- kv postprocess -> kcat bf16 (T,576) ----
__global__ __launch_bounds__(256) void k_kv_post2(const float* __restrict__ kv,
                                                  const float* __restrict__ lnw,
                                                  const float* __restrict__ cosT,
                                                  const float* __restrict__ sinT,
                                                  ushortT* __restrict__ kcat) {
    int t = blockIdx.x, tid = threadIdx.x;
    const float* row = kv + (size_t)t * 576;
    float v0 = row[tid], v1 = row[tid + 256];
    float s = v0 * v0 + v1 * v1;
    for (int o = 32; o > 0; o >>= 1) s += __shfl_down(s, o);
    __shared__ float sm[4];
    if ((tid & 63) == 0) sm[tid >> 6] = s;
    __syncthreads();
    float tot = sm[0] + sm[1] + sm[2] + sm[3];
    float inv = 1.f / sqrtf(tot / 512.f + 1e-6f);
    ushortT* out = kcat + (size_t)t * 576;
    out[tid] = f2bf(v0 * inv * lnw[tid]);
    out[tid + 256] = f2bf(v1 * inv * lnw[tid + 256]);
    if (tid < 32) {
        float c = cosT[t * 32 + tid], sn = sinT[t * 32 + tid];
        float x1 = row[512 + 2 * tid], x2 = row[512 + 2 * tid + 1];
        out[512 + 2 * tid] = f2bf(x1 * c - x2 * sn);
        out[512 + 2 * tid + 1] = f2bf(x2 * c + x1 * sn);
    }
}

// ------- rope on q_pe (bf16 qfull) -> qcat[...,512:576] (SCALE folded) ------------------
__global__ __launch_bounds__(256) void k_rope_q2(const ushortT* __restrict__ qfull,
                                                 const float* __restrict__ cosT,
                                                 const float* __restrict__ sinT,
                                                 ushortT* __restrict__ qcat) {
    int b = blockIdx.x * 8 + (threadIdx.x >> 5);
    int i = threadIdx.x & 31;
    int t = b >> 5, h = b & 31;
    const ushortT* p = qfull + (size_t)b * 192 + 128;
    float c = cosT[t * 32 + i], s = sinT[t * 32 + i];
    float x1 = bf2f(p[2 * i]), x2 = bf2f(p[2 * i + 1]);
    ushortT* q = qcat + (size_t)t * 18432 + h * 576 + 512;
    q[2 * i] = f2bf((x1 * c - x2 * s) * SCALE_F);
    q[2 * i + 1] = f2bf((x2 * c + x1 * s) * SCALE_F);
}

// ---- indexer k: sum 16 split-K partials + layernorm + neox rope + fp8 quant -> bytes ----
__global__ __launch_bounds__(128) void k_ki_post16(const float* __restrict__ kp,
                                                   const float* __restrict__ g,
                                                   const float* __restrict__ be,
                                                   const float* __restrict__ cosT,
                                                   const float* __restrict__ sinT,
                                                   uchar* __restrict__ ki8,
                                                   float* __restrict__ kscale) {
    int t = blockIdx.x, i = threadIdx.x;
    float x = 0.f;
#pragma unroll
    for (int z = 0; z < 16; ++z) x += kp[(size_t)z * 262144 + (size_t)t * 128 + i];
    float s = x;
    for (int o = 32; o > 0; o >>= 1) s += __shfl_down(s, o);
    __shared__ float sm[2];
    if ((i & 63) == 0) sm[i >> 6] = s;
    __syncthreads();
    float mean = (sm[0] + sm[1]) / 128.f;
    float d = x - mean;
    float s2 = d * d;
    for (int o = 32; o > 0; o >>= 1) s2 += __shfl_down(s2, o);
    __shared__ float sv[2];
    if ((i & 63) == 0) sv[i >> 6] = s2;
    __syncthreads();
    float var = (sv[0] + sv[1]) / 128.f;
    float nrm = d * (1.f / sqrtf(var + 1e-6f)) * g[i] + be[i];
    __shared__ float buf[128];
    buf[i] = nrm;
    __syncthreads();
    float out;
    if (i < 32)      out = buf[i] * cosT[t * 32 + i] - buf[i + 32] * sinT[t * 32 + i];
    else if (i < 64) out = buf[i] * cosT[t * 32 + i - 32] + buf[i - 32] * sinT[t * 32 + i - 32];
    else             out = nrm;
    float a = fabsf(out);
    for (int o = 32; o > 0; o >>= 1) a = fmaxf(a, __shfl_down(a, o));
    __shared__ float am[2];
    if ((i & 63) == 0) am[i >> 6] = a;
    __syncthreads();
    float amax = fmaxf(fmaxf(am[0], am[1]), 1e-10f);
    float scale = __int_as_float((((int)ceilf(log2f(amax / 448.f))) + 127) << 23);
    ki8[(size_t)t * 128 + i] = enc_e4m3(q_e4m3(out / scale));
    if (i == 0) kscale[t] = scale;
}

// ---- indexer q: bf16 GEMM result + neox rope + fp8 quant -> bytes -----------------------
__global__ __launch_bounds__(128) void k_qi_post_bf(const ushortT* __restrict__ qi_bf,
                                                    const float* __restrict__ cosT,
                                                    const float* __restrict__ sinT,
                                                    uchar* __restrict__ qi8,
                                                    float* __restrict__ qscale) {
    int b = blockIdx.x;
    int t = b >> 5;
    int i = threadIdx.x;
    float x = bf2f(qi_bf[(size_t)b * 128 + i]);
    __shared__ float buf[128];
    buf[i] = x;
    __syncthreads();
    float out;
    if (i < 32)      out = buf[i] * cosT[t * 32 + i] - buf[i + 32] * sinT[t * 32 + i];
    else if (i < 64) out = buf[i] * cosT[t * 32 + i - 32] + buf[i - 32] * sinT[t * 32 + i - 32];
    else             out = x;
    float a = fabsf(out);
    for (int o = 32; o > 0; o >>= 1) a = fmaxf(a, __shfl_down(a, o));
    __shared__ float am[2];
    if ((i & 63) == 0) am[i >> 6] = a;
    __syncthreads();
    float amax = fmaxf(fmaxf(am[0], am[1]), 1e-10f);
    float scale = __int_as_float((((int)ceilf(log2f(amax / 448.f))) + 127) << 23);
    qi8[(size_t)b * 128 + i] = enc_e4m3(q_e4m3(out / scale));
    if (i == 0) qscale[b] = scale;
}

// ---------------- indexer weights ----------------
__global__ __launch_bounds__(256) void k_wiw(const float* __restrict__ hs,
                                             const float* __restrict__ W_iw,
                                             const float* __restrict__ qscale,
                                             float* __restrict__ wts) {
    int t = blockIdx.x, tid = threadIdx.x;
    __shared__ float hr[2048];
    for (int i = tid; i < 2048; i += 256) hr[i] = hs[(size_t)t * 2048 + i];
    __syncthreads();
    int h = tid & 31, p = tid >> 5;
    float s = 0;
    for (int k = p * 256; k < p * 256 + 256; ++k) s = fmaf(hr[k], W_iw[(size_t)k * 32 + h], s);
    __shared__ float part[8][32];
    part[p][h] = s;
    __syncthreads();
    if (tid < 32) {
        float tot = 0;
#pragma unroll
        for (int pp = 0; pp < 8; ++pp) tot += part[pp][tid];
        const float a = (float)0.08838834764831845;   // 128^-0.5
        const float b = (float)0.1767766952966369;    // 32^-0.5
        wts[t * 32 + tid] = tot * qscale[t * 32 + tid] * a * b;
    }
}

// ======== indexer score via fp8 MFMA ====
__global__ __launch_bounds__(256) void k_score8(const uchar* __restrict__ qi8,
                                                const uchar* __restrict__ ki8,
                                                const float* __restrict__ kscale,
                                                const float* __restrict__ wts,
                                                float* __restrict__ score) {
    int b = blockIdx.x;
    int ti = (int)((sqrtf(8.f * b + 1.f) - 1.f) * 0.5f);
    while ((ti + 1) * (ti + 2) / 2 <= b) ++ti;
    while (ti * (ti + 1) / 2 > b) --ti;
    int si = b - ti * (ti + 1) / 2;
    int t0 = ti * 32, s0 = si * 32;
    int tid = threadIdx.x, lane = tid & 63, w = tid >> 6;
    int qt = w >> 1, qs = w & 1;
    int col = lane & 15, g = lane >> 4;

    __shared__ __align__(16) uchar k8s[4096];
    __shared__ __align__(16) uchar q8s[32768];
    __shared__ float wts_s[32][33];

    {
        int row = tid >> 3, inner = tid & 7;
        uint4 v = *(const uint4*)(ki8 + (size_t)(s0 + row) * 128 + inner * 16);
        *(uint4*)(k8s + ((row * 128 + inner * 16) ^ ((row & 7) << 4))) = v;
    }
    for (int c = tid; c < 1024; c += 256) {
        int tl = c >> 5, h = c & 31;
        wts_s[tl][h] = wts[(size_t)(t0 + tl) * 32 + h];
    }

    float ksc = kscale[s0 + qs * 16 + col];
    int arow = qt * 16 + col;
    int brow = qs * 16 + col;
    float sacc[4] = {0.f, 0.f, 0.f, 0.f};

    for (int h0 = 0; h0 < 32; h0 += 8) {
        __syncthreads();
        for (int c = tid; c < 2048; c += 256) {
            int hh = c >> 8, row = (c >> 3) & 31, inner = c & 7;
            uint4 v = *(const uint4*)(qi8 + ((size_t)(t0 + row) * 32 + h0 + hh) * 128 + inner * 16);
            *(uint4*)(q8s + hh * 4096 + ((row * 128 + inner * 16) ^ ((row & 7) << 4))) = v;
        }
        __syncthreads();
#pragma unroll
        for (int hh = 0; hh < 8; ++hh) {
            f32x4 c4 = (f32x4){0.f, 0.f, 0.f, 0.f};
#pragma unroll
            for (int kk = 0; kk < 4; ++kk) {
                long long a = *(const long long*)(q8s + hh * 4096 +
                              ((arow * 128 + kk * 32 + g * 8) ^ ((arow & 7) << 4)));
                long long bb = *(const long long*)(k8s +
                              ((brow * 128 + kk * 32 + g * 8) ^ ((brow & 7) << 4)));
                c4 = __builtin_amdgcn_mfma_f32_16x16x32_fp8_fp8(a, bb, c4, 0, 0, 0);
            }
            int h = h0 + hh;
#pragma unroll
            for (int r = 0; r < 4; ++r)
                sacc[r] = fmaf(fmaxf(c4[r] * ksc, 0.f), wts_s[qt * 16 + g * 4 + r][h], sacc[r]);
        }
    }
    int t = t0 + qt * 16 + g * 4;
    int s = s0 + qs * 16 + col;
#pragma unroll
    for (int r = 0; r < 4; ++r)
        if (s <= t + r) score[(size_t)(t + r) * T_N + s] = sacc[r];
}

// ---------------- top-512 per row (stable ties) --------------------------
__global__ __launch_bounds__(256) void k_topk(const float* __restrict__ score,
                                              int* __restrict__ tki, int* __restrict__ tkc) {
    int t = blockIdx.x;
    int n = t + 1;
    int tid = threadIdx.x;
    if (n <= TOPK_N) {
        for (int i = tid; i < n; i += 256) tki[(size_t)t * TOPK_N + i] = i;
        if (tid == 0) tkc[t] = n;
        return;
    }
    __shared__ unsigned keys[2048];
    const float* row = score + (size_t)t * T_N;
    for (int i = tid; i < n; i += 256) {
        float f = row[i] + 0.f;
        unsigned u = __float_as_uint(f);
        u = (u & 0x80000000u) ? ~u : (u | 0x80000000u);
        keys[i] = u;
    }
    __shared__ int hist[256];
    __shared__ unsigned sh_prefix;
    __shared__ int sh_need;
    if (tid == 0) { sh_prefix = 0u; sh_need = TOPK_N; }
    __syncthreads();
    unsigned maskHi = 0;
    for (int level = 3; level >= 0; --level) {
        hist[tid] = 0;
        __syncthreads();
        unsigned prefix = sh_prefix;
        int shift = level * 8;
        for (int i = tid; i < n; i += 256) {
            unsigned kk = keys[i];
            if ((kk & maskHi) == prefix) atomicAdd(&hist[(kk >> shift) & 255], 1);
        }
        __syncthreads();
        if (tid == 0) {
            int need = sh_need, cum = 0, bsel = 255;
            for (int bb = 255; bb >= 0; --bb) {
                if (cum + hist[bb] >= need) { bsel = bb; break; }
                cum += hist[bb];
            }
            sh_need = need - cum;
            sh_prefix = prefix | ((unsigned)bsel << shift);
        }
        __syncthreads();
        maskHi |= (0xFFu << shift);
    }
    unsigned thr = sh_prefix;
    int needEq = sh_need;
    int base = tid * 8;
    int eqcnt = 0;
#pragma unroll
    for (int j = 0; j < 8; ++j) {
        int i = base + j;
        if (i < n && keys[i] == thr) eqcnt++;
    }
    __shared__ int scn[256];
    scn[tid] = eqcnt;
    __syncthreads();
    for (int off = 1; off < 256; off <<= 1) {
        int add = (tid >= off) ? scn[tid - off] : 0;
        __syncthreads();
        scn[tid] += add;
        __syncthreads();
    }
    int eq_excl = scn[tid] - eqcnt;
    int acnt = 0;
    {
        int eqr = eq_excl;
#pragma unroll
        for (int j = 0; j < 8; ++j) {
            int i = base + j;
            if (i < n) {
                unsigned kk = keys[i];
                bool a = (kk > thr) || (kk == thr && eqr < needEq);
                if (kk == thr) eqr++;
                if (a) acnt++;
            }
        }
    }
    __syncthreads();
    scn[tid] = acnt;
    __syncthreads();
    for (int off = 1; off < 256; off <<= 1) {
        int add = (tid >= off) ? scn[tid - off] : 0;
        __syncthreads();
        scn[tid] += add;
        __syncthreads();
    }
    int pos = scn[tid] - acnt;
    {
        int eqr = eq_excl;
#pragma unroll
        for (int j = 0; j < 8; ++j) {
            int i = base + j;
            if (i < n) {
                unsigned kk = keys[i];
                bool a = (kk > thr) || (kk == thr && eqr < needEq);
                if (kk == thr) eqr++;
                if (a) tki[(size_t)t * TOPK_N + (pos++)] = i;
            }
        }
    }
    if (tid == 0) tkc[t] = TOPK_N;
}

// ======== fused sparse MFMA attention, single-pass flash-style (round-13 body) ==========
// Coalesced gather lane map (skey = w*8 + lane>>3, part = lane&7): 8 consecutive lanes
// read 128 consecutive bytes of one kcat row. kbV: dim-dependent key-group rotation.
__global__ __launch_bounds__(256, 2) void k_attn_mfma(const ushortT* __restrict__ qcat,
                                                      const ushortT* __restrict__ kcat,
                                                      const int* __restrict__ tki,
                                                      const int* __restrict__ tkc,
                                                      ushortT* __restrict__ olat) {
    int t = blockIdx.x;
    int tid = threadIdx.x;
    int lane = tid & 63;
    int w = tid >> 6;                 // 4 waves
    int S = tkc[t];
    int nchunk = (S + 31) >> 5;

    __shared__ int idx_s[512];
    __shared__ __align__(16) ushortT kbK[18 * 1024];  // [kk][32 keys][32 dims] 36864B
    __shared__ __align__(16) ushortT kbV[512 * 32];   // [512 dims][32 keys, grp-rotated]
    __shared__ __align__(16) ushortT psc[32 * 32];    // [32 heads][32 keys]     2048B
    __shared__ float red[64];                         // [head][nt] partial sums

    idx_s[tid] = (tid < S) ? tki[(size_t)t * TOPK_N + tid] : 0;
    idx_s[tid + 256] = (tid + 256 < S) ? tki[(size_t)t * TOPK_N + tid + 256] : 0;

    int lr = lane & 15, lk = lane >> 4;
    int mt = w >> 1, nt = w & 1;      // score quadrant: heads mt*16, keys nt*16

    bf16x8 qf[18];
    {
        const ushortT* qrow = qcat + (size_t)t * 18432 + (size_t)(mt * 16 + lr) * 576 + lk * 8;
#pragma unroll
        for (int kk = 0; kk < 18; ++kk) qf[kk] = *(const bf16x8*)(qrow + kk * 32);
    }
    __syncthreads();

    // coalesced staging map: 8 lanes cover 128 consecutive bytes of one key row
    int skey = (w << 3) | (lane >> 3);   // 0..31
    int part = lane & 7;                 // 16B chunk index within each 128B group

    f32x4 oa[2][8];
#pragma unroll
    for (int i = 0; i < 2; ++i)
#pragma unroll
        for (int j = 0; j < 8; ++j) oa[i][j] = (f32x4){0.f, 0.f, 0.f, 0.f};
    float sm_[4] = {0.f, 0.f, 0.f, 0.f};

    uint4 sv[9];
    {   // prefetch chunk 0
        bool ok = skey < S;
        const ushortT* g = kcat + (size_t)idx_s[skey] * 576 + part * 8;
#pragma unroll
        for (int i = 0; i < 9; ++i) {
            uint4 v = {0, 0, 0, 0};
            if (ok) v = *(const uint4*)(g + i * 64);
            sv[i] = v;
        }
    }

    for (int p = 0; p < nchunk; ++p) {
        // ---- stage chunk p: K-layout + V-transposed (grp-rotated) ----
#pragma unroll
        for (int i = 0; i < 9; ++i) {
            int dg = part + i * 8;
            int off = ((skey * 64 + (dg & 3) * 16) ^ ((skey & 7) << 4)) + (dg >> 2) * 2048;
            *(uint4*)((char*)kbK + off) = sv[i];
        }
#pragma unroll
        for (int i = 0; i < 8; ++i) {           // dg < 64: V dims only
            int dg = part + i * 8;
            int inner = ((((skey >> 3) + (dg & 3)) & 3) << 4) | ((skey & 7) << 1);
            const ushortT* pv = (const ushortT*)&sv[i];
#pragma unroll
            for (int j = 0; j < 8; ++j) {       // dim = dg*8+j, dim&7 == j
                int off = ((dg * 8 + j) * 64 + inner) ^ (j << 4);
                *(ushortT*)((char*)kbV + off) = pv[j];
            }
        }
        __syncthreads();
        // issue prefetch AFTER the barrier: latency hides under score MFMA + exp
        if (p + 1 < nchunk) {
            int gk = (p + 1) * 32 + skey;
            bool ok = gk < S;
            const ushortT* g = kcat + (size_t)idx_s[gk] * 576 + part * 8;
#pragma unroll
            for (int i = 0; i < 9; ++i) {
                uint4 v = {0, 0, 0, 0};
                if (ok) v = *(const uint4*)(g + i * 64);
                sv[i] = v;
            }
        }
        // ---- score: C[16h][16k] for quadrant (mt, nt) ----
        f32x4 acc = (f32x4){0.f, 0.f, 0.f, 0.f};
        int brow = nt * 16 + lr;
#pragma unroll
        for (int kk = 0; kk < 18; ++kk) {
            bf16x8 b = *(const bf16x8*)((const char*)kbK + kk * 2048 +
                        ((brow * 64 + lk * 16) ^ ((brow & 7) << 4)));
            acc = __builtin_amdgcn_mfma_f32_16x16x32_bf16(qf[kk], b, acc, 0, 0, 0);
        }
        // ---- exp (m=0), accumulate sums, write P chunk ----
        int key_g = p * 32 + nt * 16 + lr;
        int hb = mt * 16 + lk * 4;
#pragma unroll
        for (int r = 0; r < 4; ++r) {
            float e = (key_g < S) ? expf(acc[r]) : 0.f;
            sm_[r] += e;
            int head = hb + r;
            int off = (head * 64 + (nt * 16 + lr) * 2) ^ ((head & 7) << 4);
            *(ushortT*)((char*)psc + off) = f2bf(e);
        }
        __syncthreads();
        // ---- PV: all 32 heads x this wave's 128 dims, K = 32 chunk keys ----
#pragma unroll
        for (int m2 = 0; m2 < 2; ++m2) {
            int arow = m2 * 16 + lr;
            bf16x8 a = *(const bf16x8*)((const char*)psc +
                        ((arow * 64 + lk * 16) ^ ((arow & 7) << 4)));
#pragma unroll
            for (int n2 = 0; n2 < 8; ++n2) {
                int dim = w * 128 + n2 * 16 + lr;
                int grp = (lk + ((dim >> 3) & 3)) & 3;
                bf16x8 b = *(const bf16x8*)((const char*)kbV +
                            ((dim * 64 + (grp << 4)) ^ ((dim & 7) << 4)));
                oa[m2][n2] = __builtin_amdgcn_mfma_f32_16x16x32_bf16(a, b, oa[m2][n2], 0, 0, 0);
            }
        }
        __syncthreads();
    }
    // ---- reduce per-head sums: over lr lanes, then across nt waves via LDS ----
#pragma unroll
    for (int off = 1; off < 16; off <<= 1)
#pragma unroll
        for (int r = 0; r < 4; ++r) sm_[r] += __shfl_xor(sm_[r], off);
    if (lr == 0) {
#pragma unroll
        for (int r = 0; r < 4; ++r) red[(mt * 16 + lk * 4 + r) * 2 + nt] = sm_[r];
    }
    __syncthreads();
    // ---- normalize, stage [32 heads][512 dims] bf16 into kbK (swizzled) ----
#pragma unroll
    for (int m2 = 0; m2 < 2; ++m2)
#pragma unroll
        for (int r = 0; r < 4; ++r) {
            int head = m2 * 16 + lk * 4 + r;
            float dvv = 1.f / (red[head * 2] + red[head * 2 + 1]);
#pragma unroll
            for (int n2 = 0; n2 < 8; ++n2) {
                int dim = w * 128 + n2 * 16 + lr;
                int off = (head * 1024 + dim * 2) ^ ((head & 7) << 4);
                *(ushortT*)((char*)kbK + off) = f2bf(oa[m2][n2][r] * dvv);
            }
        }
    __syncthreads();
    // ---- coalesced store: 4 consecutive lanes cover 64B of one head row ----
    ushortT* orow = olat + (size_t)t * 18432;
#pragma unroll
    for (int i = 0; i < 8; ++i) {
        int idx = i * 256 + tid;
        int head = idx >> 6, seg = idx & 63;
        uint4 v = *(const uint4*)((const char*)kbK +
                   ((head * 1024 + seg * 16) ^ ((head & 7) << 4)));
        *(uint4*)(orow + head * 512 + seg * 8) = v;
    }
}

// ---------------- launch ----------------
extern "C" void kernel_launch(void* const* d_in, const int* in_sizes, int n_in,
                              void* d_out, int out_size, void* d_ws, size_t ws_size,
                              hipStream_t stream) {
    (void)in_sizes; (void)n_in; (void)out_size; (void)ws_size;
    const int*   positions = (const int*)d_in[0];
    const float* hs        = (const float*)d_in[1];
    const float* q_c       = (const float*)d_in[2];
    const float* kv_lora   = (const float*)d_in[3];
    const float* W_qb      = (const float*)d_in[4];
    const float* W_kvb     = (const float*)d_in[5];
    const float* W_o       = (const float*)d_in[6];
    const float* kv_ln     = (const float*)d_in[7];
    const float* W_iq      = (const float*)d_in[8];
    const float* W_ik      = (const float*)d_in[9];
    const float* gamma     = (const float*)d_in[10];
    const float* beta      = (const float*)d_in[11];
    const float* W_iw      = (const float*)d_in[12];

    float* ws = (float*)d_ws;
    // workspace (float offsets); high-water 50,204,672 fl = 200.8 MB (< 218.4 proven)
    float*   cosT   = ws;                          // 65,536
    float*   sinT   = ws + 65536;                  // 65,536
    int*     tki    = (int*)(ws + 131072);         // 1,048,576
    int*     tkc    = (int*)(ws + 1179648);        // 2,048
    ushortT* kcat   = (ushortT*)(ws + 1181696);    // 589,824 fl
    float*   kscale = ws + 1771520;                // 2,048
    float*   qscale = ws + 1773568;                // 65,536
    float*   wts    = ws + 1839104;                // 65,536
    uchar*   qi8    = (uchar*)(ws + 1904640);      // 2,097,152 fl (8 MB bytes)
    uchar*   ki8    = (uchar*)(ws + 4001792);      // 65,536 fl
    // qc_bf persistent through step 11:
    ushortT* qc_bf  = (ushortT*)(ws + 4067328);    // 1,572,864 fl [2a -> read 4, 11]
    // REGION R1 5,640,192..20,844,544, time-multiplexed:
    ushortT* wiq_t  = (ushortT*)(ws + 5640192);    // 3,145,728 fl [2b -> dead after 4]
    float*   kip    = ws + 8785920;                // 4,194,304  [2 -> dead after 3]
    ushortT* qi_bf  = (ushortT*)(ws + 12980224);   // 4,194,304 fl [4 -> dead after 5]
    ushortT* wqb_t  = (ushortT*)(ws + 5640192);    // 4,718,592 fl [10, over wiq_t/kip]
    ushortT* wuk_t  = (ushortT*)(ws + 10358784);   // 1,048,576 fl [10 -> dead after 13]
    ushortT* wuv_t  = (ushortT*)(ws + 11407360);   // 1,048,576 fl [10 -> read at 15]
    ushortT* wo_t   = (ushortT*)(ws + 12980224);   // 4,194,304 fl [10, over qi_bf]
    // score / vbuf slot:
    float*   score  = ws + 20844544;               // 4,194,304 [7 -> dead after 8]
    ushortT* vbuf   = (ushortT*)(ws + 20844544);   // 4,194,304 fl [15 -> 16]
    // persistent tail:
    ushortT* qfull_bf = (ushortT*)(ws + 25038848); // 6,291,456 fl [11 -> 12,13]
    ushortT* qcat   = (ushortT*)(ws + 31330304);   // 18,874,368 fl; o written in place (14)

    // 1. rope tables
    k_rope_tables<<<T_N, 32, 0, stream>>>(positions, cosT, sinT);
    // 2a/2b. bf16 casts for the q-path GEMMs
    k_cast4<<<3072, 256, 0, stream>>>(q_c, qc_bf, T_N * QLORA_N / 4);
    k_tcast<<<dim3(48, 128, 1), 256, 0, stream>>>(W_iq, wiq_t, 4096, 0, 0, 1536, 0);
    // 2. indexer k: hs @ W_ik (2048x128x2048), split-K x16 -> partials (f32, exact)
    gemm128<false><<<dim3(1, 16, 16), 256, 0, stream>>>(
        hs, W_ik, kip, T_N, 128, 128, HID_N, 128, 128, 128, 16384, 262144);
    // 3. sum partials + LN + neox rope + fp8 quant -> ki8 bytes
    k_ki_post16<<<T_N, 128, 0, stream>>>(kip, gamma, beta, cosT, sinT, ki8, kscale);
    // 4. indexer q: qc_bf @ wiq_t (bf16 MFMA) -> qi_bf (2048x4096)
    bgemm<true><<<dim3(32, 16, 1), 256, 0, stream>>>(
        qc_bf, wiq_t, qi_bf, QLORA_N, QLORA_N, QLORA_N, 4096, 0, 0, 0, 1.f);
    // 5. neox rope + fp8 quant -> qi8 bytes
    k_qi_post_bf<<<T_N * IDX_H_N, 128, 0, stream>>>(qi_bf, cosT, sinT, qi8, qscale);
    // 6. indexer weights
    k_wiw<<<T_N, 256, 0, stream>>>(hs, W_iw, qscale, wts);
    // 7. indexer score via fp8 MFMA
    k_score8<<<2080, 256, 0, stream>>>(qi8, ki8, kscale, wts, score);
    // 8. top-512
    k_topk<<<T_N, 256, 0, stream>>>(score, tki, tkc);
    // 9. kv rms_norm + k_pe rope -> kcat bf16
    k_kv_post2<<<T_N, 256, 0, stream>>>(kv_lora, kv_ln, cosT, sinT, kcat);
    // 10. remaining weight transposes (R1 free again)
    k_tcast<<<dim3(48, 192, 1), 256, 0, stream>>>(W_qb, wqb_t, 6144, 0, 0, 1536, 0);
    k_wuk_cast<<<8192, 256, 0, stream>>>(W_kvb, wuk_t);
    k_tcast<<<dim3(16, 4, 32), 256, 0, stream>>>(W_kvb, wuv_t, 8192, 128, 256, 512, 65536);
    k_tcast<<<dim3(128, 64, 1), 256, 0, stream>>>(W_o, wo_t, 2048, 0, 0, 4096, 0);
    // 11. qfull = q_c @ W_qb (bf16 MFMA) -> bf16 (T,32,192)
    bgemm<true><<<dim3(48, 16, 1), 256, 0, stream>>>(
        qc_bf, wqb_t, qfull_bf, QLORA_N, QLORA_N, QLORA_N, 6144, 0, 0, 0, 1.f);
    // 12. rope q_pe -> qcat[...,512:576]
    k_rope_q2<<<T_N * H_N / 8, 256, 0, stream>>>(qfull_bf, cosT, sinT, qcat);
    // 13. q_lat = q_nope @ W_UK^T per head -> qcat[...,0:512] (SCALE folded)
    bgemm<true><<<dim3(4, 16, 32), 256, 0, stream>>>(
        qfull_bf, wuk_t, qcat, NOPE_N, 6144, 128, 18432, 192, 65536, 576, SCALE_F);
    // 14. fused sparse MFMA attention (single-pass) -> o written in place into qcat rows
    k_attn_mfma<<<T_N, 256, 0, stream>>>(qcat, kcat, tki, tkc, qcat);
    // 15. v = o @ W_UV per head -> vbuf bf16 (T,4096)
    bgemm<true><<<dim3(1, 16, 32), 256, 0, stream>>>(
        qcat, wuv_t, vbuf, KVLORA_N, 18432, 512, 4096, 512, 65536, 128, 1.f);
    // 16. out = vbuf @ W_o -> f32
    bgemm<false><<<dim3(16, 16, 1), 256, 0, stream>>>(
        vbuf, wo_t, (float*)d_out, H_N * VD_N, 4096, 4096, HID_N, 0, 0, 0, 1.f);
}

// Round 16
// 636.015 us; speedup vs baseline: 1.1985x; 1.0183x over previous
//
#include <hip/hip_runtime.h>
#include <hip/hip_bf16.h>

// ---------------- constants ----------------
#define T_N    2048
#define H_N    32
#define NOPE_N 128
#define ROPE_N 64
#define VD_N   128
#define QLORA_N 1536
#define KVLORA_N 512
#define IDX_H_N 32
#define IDX_D_N 128
#define TOPK_N 512
#define HID_N  2048

typedef __attribute__((ext_vector_type(8))) short bf16x8;
typedef __attribute__((ext_vector_type(4))) float f32x4;
typedef unsigned short ushortT;
typedef unsigned char uchar;

#define SCALE_F 0.07216878364870323f  // (NOPE+ROPE)^-0.5 = 192^-0.5

static __device__ __forceinline__ ushortT f2bf(float x) {
    __hip_bfloat16 b = __float2bfloat16(x);
    return *(ushortT*)&b;
}
static __device__ __forceinline__ float bf2f(ushortT u) {
    __hip_bfloat16 b = *(__hip_bfloat16*)&u;
    return __bfloat162float(b);
}

#define GLL16(g, l) __builtin_amdgcn_global_load_lds( \
    (const __attribute__((address_space(1))) unsigned int*)(g), \
    (__attribute__((address_space(3))) unsigned int*)(l), 16, 0, 0)

// exact RNE float -> e4m3fn grid
static __device__ __forceinline__ float q_e4m3(float x) {
    float ax = fabsf(x);
    unsigned b = __float_as_uint(ax);
    int e = (int)(b >> 23) - 126;
    int ue = (e - 4 > -9) ? (e - 4) : -9;
    float ulp = __int_as_float((ue + 127) << 23);
    float q = rintf(ax / ulp) * ulp;
    return copysignf(q, x);
}

// encode a value ALREADY on the e4m3fn grid (|q|<=448) to its fp8 byte
static __device__ __forceinline__ uchar enc_e4m3(float q) {
    unsigned b = __float_as_uint(q);
    unsigned s = (b >> 31) << 7;
    float ax = fabsf(q);
    if (ax == 0.f) return (uchar)s;
    int e = (int)((b >> 23) & 255) - 127;   // q = 1.m * 2^e
    if (e >= -6) {
        unsigned m = (b >> 20) & 7;         // exact: grid value has 3 mantissa bits
        return (uchar)(s | ((unsigned)(e + 7) << 3) | m);
    }
    unsigned M = (unsigned)rintf(ax * 512.f);  // subnormal: M * 2^-9, M in 1..7
    return (uchar)(s | M);
}

// ---------------- rope tables ----------------
__global__ void k_rope_tables(const int* __restrict__ pos, float* __restrict__ cosT,
                              float* __restrict__ sinT) {
    int t = blockIdx.x, i = threadIdx.x;
    double inv = 1.0 / pow(10000.0, (double)i / 32.0);
    double ang = (double)pos[t] * inv;
    cosT[t * 32 + i] = (float)cos(ang);
    sinT[t * 32 + i] = (float)sin(ang);
}

// ---------------- generic 128x128 f32 GEMM (BK=8), batched/split-K via blockIdx.z -------
template <bool BT>
__global__ __launch_bounds__(256) void gemm128(
    const float* __restrict__ A, const float* __restrict__ B, float* __restrict__ C,
    int M, int N, int K, int lda, int ldb, int ldc,
    long batchOffA, long batchOffB, long batchOffC) {
    const float* Ab = A + (size_t)batchOffA * blockIdx.z;
    const float* Bb = B + (size_t)batchOffB * blockIdx.z;
    int bm = blockIdx.y * 128, bn = blockIdx.x * 128;
    int tid = threadIdx.x;
    __shared__ float As[8][128];
    __shared__ float Bs[8][128];
    float acc[8][8];
#pragma unroll
    for (int i = 0; i < 8; ++i)
#pragma unroll
        for (int j = 0; j < 8; ++j) acc[i][j] = 0.f;
    int tx = tid & 15, ty = tid >> 4;
    int ar = tid >> 1, ak = (tid & 1) * 4;
    for (int k0 = 0; k0 < K; k0 += 8) {
        float4 av = *(const float4*)(Ab + (size_t)(bm + ar) * lda + k0 + ak);
        As[ak + 0][ar] = av.x; As[ak + 1][ar] = av.y;
        As[ak + 2][ar] = av.z; As[ak + 3][ar] = av.w;
        if (BT) {
            int n = tid >> 1, kk = (tid & 1) * 4;
            float4 bv = *(const float4*)(Bb + (size_t)(bn + n) * ldb + k0 + kk);
            Bs[kk + 0][n] = bv.x; Bs[kk + 1][n] = bv.y;
            Bs[kk + 2][n] = bv.z; Bs[kk + 3][n] = bv.w;
        } else {
            int kk = tid >> 5, n = (tid & 31) * 4;
            float4 bv = *(const float4*)(Bb + (size_t)(k0 + kk) * ldb + bn + n);
            Bs[kk][n + 0] = bv.x; Bs[kk][n + 1] = bv.y;
            Bs[kk][n + 2] = bv.z; Bs[kk][n + 3] = bv.w;
        }
        __syncthreads();
#pragma unroll
        for (int kk = 0; kk < 8; ++kk) {
            float4 a0 = *(const float4*)(&As[kk][ty * 8]);
            float4 a1 = *(const float4*)(&As[kk][ty * 8 + 4]);
            float4 b0 = *(const float4*)(&Bs[kk][tx * 8]);
            float4 b1 = *(const float4*)(&Bs[kk][tx * 8 + 4]);
            float a[8] = {a0.x, a0.y, a0.z, a0.w, a1.x, a1.y, a1.z, a1.w};
            float b[8] = {b0.x, b0.y, b0.z, b0.w, b1.x, b1.y, b1.z, b1.w};
#pragma unroll
            for (int i = 0; i < 8; ++i)
#pragma unroll
                for (int j = 0; j < 8; ++j) acc[i][j] = fmaf(a[i], b[j], acc[i][j]);
        }
        __syncthreads();
    }
    size_t cbase = (size_t)batchOffC * blockIdx.z;
#pragma unroll
    for (int i = 0; i < 8; ++i) {
        size_t r = bm + ty * 8 + i;
#pragma unroll
        for (int j = 0; j < 8; ++j) {
            size_t c = bn + tx * 8 + j;
            C[cbase + r * (size_t)ldc + c] = acc[i][j];
        }
    }
}

// ======== bf16 NT MFMA GEMM (m97 structure) =============================================
// BK=32, double-buffered LDS, global_load_lds width-16 staging with linear LDS dest +
// inverse-swizzled global source (involution l = p ^ (((p>>6)&3)<<4), 64B rows).
// CB16 epilogue: LDS bounce -> full-64B-line coalesced uint4 stores.
template <bool CB16>
__global__ __launch_bounds__(256) void bgemm(
    const ushortT* __restrict__ A, const ushortT* __restrict__ B, void* __restrict__ Cv,
    int K, int lda, int ldb, int ldc,
    long boffA, long boffB, long boffC, float scaleC) {
    const ushortT* Ab = A + (size_t)boffA * blockIdx.z;
    const ushortT* Bb = B + (size_t)boffB * blockIdx.z;
    int bm = blockIdx.y * 128, bn = blockIdx.x * 128;
    int tid = threadIdx.x, lane = tid & 63, w = tid >> 6;
    int wr = w >> 1, wc = w & 1;
    int lr = lane & 15, lk = lane >> 4;

    // 32KB: A dbuf = sbuf[0..8191] (ushorts), B dbuf = sbuf[8192..16383]
    __shared__ __align__(16) ushortT sbuf[16384];

    // staging sources (pre-swizzled global addresses; LDS dest stays linear)
    const ushortT* gA[2];
    const ushortT* gB[2];
    unsigned ubase[2];   // wave-uniform ushort index within one 8KB buffer
#pragma unroll
    for (int c = 0; c < 2; ++c) {
        int p = w * 2048 + c * 1024 + (lane << 4);     // physical byte in 8KB buffer
        int l = p ^ (((p >> 6) & 3) << 4);             // logical byte (involution)
        int row = l >> 6, e8 = (l & 63) >> 4;
        gA[c] = Ab + (size_t)(bm + row) * lda + e8 * 8;
        gB[c] = Bb + (size_t)(bn + row) * ldb + e8 * 8;
        ubase[c] = (unsigned)(w * 1024 + c * 512);     // ushort index (uniform part)
    }

    f32x4 acc[4][4];
#pragma unroll
    for (int i = 0; i < 4; ++i)
#pragma unroll
        for (int j = 0; j < 4; ++j) acc[i][j] = (f32x4){0.f, 0.f, 0.f, 0.f};

    int nk = K >> 5;
    int cur = 0;
    // prologue: stage tile 0 into buffer 0
#pragma unroll
    for (int c = 0; c < 2; ++c) {
        GLL16(gA[c], &sbuf[ubase[c]]);
        GLL16(gB[c], &sbuf[8192 + ubase[c]]);
    }
    for (int kt = 0; kt < nk; ++kt) {
        __syncthreads();   // drains vmcnt (stage of buf[cur] done) + prior lgkm
        if (kt + 1 < nk) {
            int ko = (kt + 1) << 5;
            int nb = (cur ^ 1) * 4096;
#pragma unroll
            for (int c = 0; c < 2; ++c) {
                GLL16(gA[c] + ko, &sbuf[nb + ubase[c]]);
                GLL16(gB[c] + ko, &sbuf[8192 + nb + ubase[c]]);
            }
        }
        int abase = cur * 8192;            // byte offset of A buffer
        int bbase = 16384 + cur * 8192;    // byte offset of B buffer
        bf16x8 af[4], bfr[4];
#pragma unroll
        for (int i = 0; i < 4; ++i) {
            int arow = wr * 64 + i * 16 + lr;
            af[i] = *(const bf16x8*)((const char*)sbuf + abase +
                     ((arow * 64 + lk * 16) ^ ((arow & 3) << 4)));
            int brow = wc * 64 + i * 16 + lr;
            bfr[i] = *(const bf16x8*)((const char*)sbuf + bbase +
                     ((brow * 64 + lk * 16) ^ ((brow & 3) << 4)));
        }
#pragma unroll
        for (int i = 0; i < 4; ++i)
#pragma unroll
            for (int j = 0; j < 4; ++j)
                acc[i][j] = __builtin_amdgcn_mfma_f32_16x16x32_bf16(af[i], bfr[j], acc[i][j], 0, 0, 0);
        cur ^= 1;
    }
    size_t cbase = (size_t)boffC * blockIdx.z;
    if (CB16) {
        __syncthreads();   // all waves done with sbuf
#pragma unroll
        for (int mi = 0; mi < 4; ++mi)
#pragma unroll
            for (int ni = 0; ni < 4; ++ni)
#pragma unroll
                for (int r = 0; r < 4; ++r) {
                    int row = wr * 64 + mi * 16 + lk * 4 + r;
                    int col = wc * 64 + ni * 16 + lr;
                    int off = (row * 256 + col * 2) ^ ((row & 7) << 4);
                    *(ushortT*)((char*)sbuf + off) = f2bf(acc[mi][ni][r] * scaleC);
                }
        __syncthreads();
        ushortT* outp = (ushortT*)Cv;
#pragma unroll
        for (int i = 0; i < 8; ++i) {
            int idx = i * 256 + tid;
            int row = idx >> 4, seg = idx & 15;
            uint4 v = *(const uint4*)((const char*)sbuf +
                       ((row * 256 + seg * 16) ^ ((row & 7) << 4)));
            *(uint4*)(outp + cbase + (size_t)(bm + row) * ldc + bn + seg * 8) = v;
        }
    } else {
#pragma unroll
        for (int mi = 0; mi < 4; ++mi)
#pragma unroll
            for (int ni = 0; ni < 4; ++ni) {
                int col = bn + wc * 64 + ni * 16 + lr;
#pragma unroll
                for (int r = 0; r < 4; ++r) {
                    int row = bm + wr * 64 + mi * 16 + lk * 4 + r;
                    ((float*)Cv)[cbase + (size_t)row * ldc + col] = acc[mi][ni][r];
                }
            }
    }
}

// ======== bf16 NT MFMA GEMM, 128x64 tile (round 16; for wide-K low-block-count GEMMs) ===
// Same BK=32 K-loop order as bgemm -> bit-identical accumulation. f32 output only.
__global__ __launch_bounds__(256) void bgemm64(
    const ushortT* __restrict__ A, const ushortT* __restrict__ B, float* __restrict__ C,
    int K, int lda, int ldb, int ldc) {
    int bm = blockIdx.y * 128, bn = blockIdx.x * 64;
    int tid = threadIdx.x, lane = tid & 63, w = tid >> 6;
    int lr = lane & 15, lk = lane >> 4;

    // 24KB: A dbuf = 2 x 4096 ushorts, B dbuf = 2 x 2048 ushorts at ushort idx 8192
    __shared__ __align__(16) ushortT sbuf[12288];

    const ushortT* gA[2];
    const ushortT* gB;
    unsigned ubaseA[2], ubaseB;
#pragma unroll
    for (int c = 0; c < 2; ++c) {
        int p = w * 2048 + c * 1024 + (lane << 4);
        int l = p ^ (((p >> 6) & 3) << 4);
        int row = l >> 6, e8 = (l & 63) >> 4;
        gA[c] = A + (size_t)(bm + row) * lda + e8 * 8;
        ubaseA[c] = (unsigned)(w * 1024 + c * 512);
    }
    {
        int p = w * 1024 + (lane << 4);                // byte in 4KB B buffer
        int l = p ^ (((p >> 6) & 3) << 4);
        int row = l >> 6, e8 = (l & 63) >> 4;
        gB = B + (size_t)(bn + row) * ldb + e8 * 8;
        ubaseB = (unsigned)(w * 512);
    }

    f32x4 acc[2][4];
#pragma unroll
    for (int i = 0; i < 2; ++i)
#pragma unroll
        for (int j = 0; j < 4; ++j) acc[i][j] = (f32x4){0.f, 0.f, 0.f, 0.f};

    int nk = K >> 5;
    int cur = 0;
#pragma unroll
    for (int c = 0; c < 2; ++c) GLL16(gA[c], &sbuf[ubaseA[c]]);
    GLL16(gB, &sbuf[8192 + ubaseB]);
    for (int kt = 0; kt < nk; ++kt) {
        __syncthreads();
        if (kt + 1 < nk) {
            int ko = (kt + 1) << 5;
#pragma unroll
            for (int c = 0; c < 2; ++c) GLL16(gA[c] + ko, &sbuf[(cur ^ 1) * 4096 + ubaseA[c]]);
            GLL16(gB + ko, &sbuf[8192 + (cur ^ 1) * 2048 + ubaseB]);
        }
        int abase = cur * 8192;            // byte offset of A buffer
        int bbase = 16384 + cur * 4096;    // byte offset of B buffer
        bf16x8 af[2], bfr[4];
#pragma unroll
        for (int i = 0; i < 2; ++i) {
            int arow = w * 32 + i * 16 + lr;
            af[i] = *(const bf16x8*)((const char*)sbuf + abase +
                     ((arow * 64 + lk * 16) ^ ((arow & 3) << 4)));
        }
#pragma unroll
        for (int j = 0; j < 4; ++j) {
            int brow = j * 16 + lr;
            bfr[j] = *(const bf16x8*)((const char*)sbuf + bbase +
                      ((brow * 64 + lk * 16) ^ ((brow & 3) << 4)));
        }
#pragma unroll
        for (int i = 0; i < 2; ++i)
#pragma unroll
            for (int j = 0; j < 4; ++j)
                acc[i][j] = __builtin_amdgcn_mfma_f32_16x16x32_bf16(af[i], bfr[j], acc[i][j], 0, 0, 0);
        cur ^= 1;
    }
#pragma unroll
    for (int i = 0; i < 2; ++i)
#pragma unroll
        for (int j = 0; j < 4; ++j) {
            int col = bn + j * 16 + lr;
#pragma unroll
            for (int r = 0; r < 4; ++r) {
                int row = bm + w * 32 + i * 16 + lk * 4 + r;
                C[(size_t)row * ldc + col] = acc[i][j][r];
            }
        }
}

// ---------------- cast / transpose helpers ----------------
__global__ __launch_bounds__(256) void k_cast4(const float* __restrict__ src,
                                               ushortT* __restrict__ dst, int n4) {
    int i = blockIdx.x * 256 + threadIdx.x;
    if (i < n4) {
        float4 v = ((const float4*)src)[i];
        ushortT o[4] = {f2bf(v.x), f2bf(v.y), f2bf(v.z), f2bf(v.w)};
        *(uint2*)(dst + (size_t)i * 4) = *(uint2*)o;
    }
}

// dst[z][b][a] bf16 = src[a*sa + b + soff + z*sz]  (sb==1), tiles 32x32
__global__ __launch_bounds__(256) void k_tcast(const float* __restrict__ src,
                                               ushortT* __restrict__ dst,
                                               long sa, long soff, long sz,
                                               long da, long dz) {
    __shared__ float tile[32][33];
    int a0 = blockIdx.x * 32, b0 = blockIdx.y * 32;
    int tx = threadIdx.x & 31, ty = threadIdx.x >> 5;
    const float* s = src + (size_t)sz * blockIdx.z + soff;
#pragma unroll
    for (int i = ty; i < 32; i += 8)
        tile[i][tx] = s[(size_t)(a0 + i) * sa + (b0 + tx)];
    __syncthreads();
    ushortT* d = dst + (size_t)dz * blockIdx.z;
#pragma unroll
    for (int i = ty; i < 32; i += 8)
        d[(size_t)(b0 + i) * da + a0 + tx] = f2bf(tile[tx][i]);
}

// wuk_t[h][r][n] = W_kvb[r][h][n]
__global__ __launch_bounds__(256) void k_wuk_cast(const float* __restrict__ wkvb,
                                                  ushortT* __restrict__ wuk) {
    int i = blockIdx.x * 256 + threadIdx.x;
    int n = i & 127, r = (i >> 7) & 511, h = i >> 16;
    wuk[i] = f2bf(wkvb[(size_t)r * 8192 + h * 256 + n]);
}

// ------- kv postprocess -> kcat bf16 (T,576) ----
__global__ __launch_bounds__(256) void k_kv_post2(const float* __restrict__ kv,
                                                  const float* __restrict__ lnw,
                                                  const float* __restrict__ cosT,
                                                  const float* __restrict__ sinT,
                                                  ushortT* __restrict__ kcat) {
    int t = blockIdx.x, tid = threadIdx.x;
    const float* row = kv + (size_t)t * 576;
    float v0 = row[tid], v1 = row[tid + 256];
    float s = v0 * v0 + v1 * v1;
    for (int o = 32; o > 0; o >>= 1) s += __shfl_down(s, o);
    __shared__ float sm[4];
    if ((tid & 63) == 0) sm[tid >> 6] = s;
    __syncthreads();
    float tot = sm[0] + sm[1] + sm[2] + sm[3];
    float inv = 1.f / sqrtf(tot / 512.f + 1e-6f);
    ushortT* out = kcat + (size_t)t * 576;
    out[tid] = f2bf(v0 * inv * lnw[tid]);
    out[tid + 256] = f2bf(v1 * inv * lnw[tid + 256]);
    if (tid < 32) {
        float c = cosT[t * 32 + tid], sn = sinT[t * 32 + tid];
        float x1 = row[512 + 2 * tid], x2 = row[512 + 2 * tid + 1];
        out[512 + 2 * tid] = f2bf(x1 * c - x2 * sn);
        out[512 + 2 * tid + 1] = f2bf(x2 * c + x1 * sn);
    }
}

// ------- rope on q_pe (bf16 qfull) -> qcat[...,512:576] (SCALE folded) ------------------
__global__ __launch_bounds__(256) void k_rope_q2(const ushortT* __restrict__ qfull,
                                                 const float* __restrict__ cosT,
                                                 const float* __restrict__ sinT,
                                                 ushortT* __restrict__ qcat) {
    int b = blockIdx.x * 8 + (threadIdx.x >> 5);
    int i = threadIdx.x & 31;
    int t = b >> 5, h = b & 31;
    const ushortT* p = qfull + (size_t)b * 192 + 128;
    float c = cosT[t * 32 + i], s = sinT[t * 32 + i];
    float x1 = bf2f(p[2 * i]), x2 = bf2f(p[2 * i + 1]);
    ushortT* q = qcat + (size_t)t * 18432 + h * 576 + 512;
    q[2 * i] = f2bf((x1 * c - x2 * s) * SCALE_F);
    q[2 * i + 1] = f2bf((x2 * c + x1 * s) * SCALE_F);
}

// ---- indexer k: sum 16 split-K partials + layernorm + neox rope + fp8 quant -> bytes ----
__global__ __launch_bounds__(128) void k_ki_post16(const float* __restrict__ kp,
                                                   const float* __restrict__ g,
                                                   const float* __restrict__ be,
                                                   const float* __restrict__ cosT,
                                                   const float* __restrict__ sinT,
                                                   uchar* __restrict__ ki8,
                                                   float* __restrict__ kscale) {
    int t = blockIdx.x, i = threadIdx.x;
    float x = 0.f;
#pragma unroll
    for (int z = 0; z < 16; ++z) x += kp[(size_t)z * 262144 + (size_t)t * 128 + i];
    float s = x;
    for (int o = 32; o > 0; o >>= 1) s += __shfl_down(s, o);
    __shared__ float sm[2];
    if ((i & 63) == 0) sm[i >> 6] = s;
    __syncthreads();
    float mean = (sm[0] + sm[1]) / 128.f;
    float d = x - mean;
    float s2 = d * d;
    for (int o = 32; o > 0; o >>= 1) s2 += __shfl_down(s2, o);
    __shared__ float sv[2];
    if ((i & 63) == 0) sv[i >> 6] = s2;
    __syncthreads();
    float var = (sv[0] + sv[1]) / 128.f;
    float nrm = d * (1.f / sqrtf(var + 1e-6f)) * g[i] + be[i];
    __shared__ float buf[128];
    buf[i] = nrm;
    __syncthreads();
    float out;
    if (i < 32)      out = buf[i] * cosT[t * 32 + i] - buf[i + 32] * sinT[t * 32 + i];
    else if (i < 64) out = buf[i] * cosT[t * 32 + i - 32] + buf[i - 32] * sinT[t * 32 + i - 32];
    else             out = nrm;
    float a = fabsf(out);
    for (int o = 32; o > 0; o >>= 1) a = fmaxf(a, __shfl_down(a, o));
    __shared__ float am[2];
    if ((i & 63) == 0) am[i >> 6] = a;
    __syncthreads();
    float amax = fmaxf(fmaxf(am[0], am[1]), 1e-10f);
    float scale = __int_as_float((((int)ceilf(log2f(amax / 448.f))) + 127) << 23);
    ki8[(size_t)t * 128 + i] = enc_e4m3(q_e4m3(out / scale));
    if (i == 0) kscale[t] = scale;
}

// ---- indexer q: bf16 GEMM result + neox rope + fp8 quant -> bytes -----------------------
__global__ __launch_bounds__(128) void k_qi_post_bf(const ushortT* __restrict__ qi_bf,
                                                    const float* __restrict__ cosT,
                                                    const float* __restrict__ sinT,
                                                    uchar* __restrict__ qi8,
                                                    float* __restrict__ qscale) {
    int b = blockIdx.x;
    int t = b >> 5;
    int i = threadIdx.x;
    float x = bf2f(qi_bf[(size_t)b * 128 + i]);
    __shared__ float buf[128];
    buf[i] = x;
    __syncthreads();
    float out;
    if (i < 32)      out = buf[i] * cosT[t * 32 + i] - buf[i + 32] * sinT[t * 32 + i];
    else if (i < 64) out = buf[i] * cosT[t * 32 + i - 32] + buf[i - 32] * sinT[t * 32 + i - 32];
    else             out = x;
    float a = fabsf(out);
    for (int o = 32; o > 0; o >>= 1) a = fmaxf(a, __shfl_down(a, o));
    __shared__ float am[2];
    if ((i & 63) == 0) am[i >> 6] = a;
    __syncthreads();
    float amax = fmaxf(fmaxf(am[0], am[1]), 1e-10f);
    float scale = __int_as_float((((int)ceilf(log2f(amax / 448.f))) + 127) << 23);
    qi8[(size_t)b * 128 + i] = enc_e4m3(q_e4m3(out / scale));
    if (i == 0) qscale[b] = scale;
}

// ---------------- indexer weights ----------------
__global__ __launch_bounds__(256) void k_wiw(const float* __restrict__ hs,
                                             const float* __restrict__ W_iw,
                                             const float* __restrict__ qscale,
                                             float* __restrict__ wts) {
    int t = blockIdx.x, tid = threadIdx.x;
    __shared__ float hr[2048];
    for (int i = tid; i < 2048; i += 256) hr[i] = hs[(size_t)t * 2048 + i];
    __syncthreads();
    int h = tid & 31, p = tid >> 5;
    float s = 0;
    for (int k = p * 256; k < p * 256 + 256; ++k) s = fmaf(hr[k], W_iw[(size_t)k * 32 + h], s);
    __shared__ float part[8][32];
    part[p][h] = s;
    __syncthreads();
    if (tid < 32) {
        float tot = 0;
#pragma unroll
        for (int pp = 0; pp < 8; ++pp) tot += part[pp][tid];
        const float a = (float)0.08838834764831845;   // 128^-0.5
        const float b = (float)0.1767766952966369;    // 32^-0.5
        wts[t * 32 + tid] = tot * qscale[t * 32 + tid] * a * b;
    }
}

// ======== indexer score via fp8 MFMA ====
__global__ __launch_bounds__(256) void k_score8(const uchar* __restrict__ qi8,
                                                const uchar* __restrict__ ki8,
                                                const float* __restrict__ kscale,
                                                const float* __restrict__ wts,
                                                float* __restrict__ score) {
    int b = blockIdx.x;
    int ti = (int)((sqrtf(8.f * b + 1.f) - 1.f) * 0.5f);
    while ((ti + 1) * (ti + 2) / 2 <= b) ++ti;
    while (ti * (ti + 1) / 2 > b) --ti;
    int si = b - ti * (ti + 1) / 2;
    int t0 = ti * 32, s0 = si * 32;
    int tid = threadIdx.x, lane = tid & 63, w = tid >> 6;
    int qt = w >> 1, qs = w & 1;
    int col = lane & 15, g = lane >> 4;

    __shared__ __align__(16) uchar k8s[4096];
    __shared__ __align__(16) uchar q8s[32768];
    __shared__ float wts_s[32][33];

    {
        int row = tid >> 3, inner = tid & 7;
        uint4 v = *(const uint4*)(ki8 + (size_t)(s0 + row) * 128 + inner * 16);
        *(uint4*)(k8s + ((row * 128 + inner * 16) ^ ((row & 7) << 4))) = v;
    }
    for (int c = tid; c < 1024; c += 256) {
        int tl = c >> 5, h = c & 31;
        wts_s[tl][h] = wts[(size_t)(t0 + tl) * 32 + h];
    }

    float ksc = kscale[s0 + qs * 16 + col];
    int arow = qt * 16 + col;
    int brow = qs * 16 + col;
    float sacc[4] = {0.f, 0.f, 0.f, 0.f};

    for (int h0 = 0; h0 < 32; h0 += 8) {
        __syncthreads();
        for (int c = tid; c < 2048; c += 256) {
            int hh = c >> 8, row = (c >> 3) & 31, inner = c & 7;
            uint4 v = *(const uint4*)(qi8 + ((size_t)(t0 + row) * 32 + h0 + hh) * 128 + inner * 16);
            *(uint4*)(q8s + hh * 4096 + ((row * 128 + inner * 16) ^ ((row & 7) << 4))) = v;
        }
        __syncthreads();
#pragma unroll
        for (int hh = 0; hh < 8; ++hh) {
            f32x4 c4 = (f32x4){0.f, 0.f, 0.f, 0.f};
#pragma unroll
            for (int kk = 0; kk < 4; ++kk) {
                long long a = *(const long long*)(q8s + hh * 4096 +
                              ((arow * 128 + kk * 32 + g * 8) ^ ((arow & 7) << 4)));
                long long bb = *(const long long*)(k8s +
                              ((brow * 128 + kk * 32 + g * 8) ^ ((brow & 7) << 4)));
                c4 = __builtin_amdgcn_mfma_f32_16x16x32_fp8_fp8(a, bb, c4, 0, 0, 0);
            }
            int h = h0 + hh;
#pragma unroll
            for (int r = 0; r < 4; ++r)
                sacc[r] = fmaf(fmaxf(c4[r] * ksc, 0.f), wts_s[qt * 16 + g * 4 + r][h], sacc[r]);
        }
    }
    int t = t0 + qt * 16 + g * 4;
    int s = s0 + qs * 16 + col;
#pragma unroll
    for (int r = 0; r < 4; ++r)
        if (s <= t + r) score[(size_t)(t + r) * T_N + s] = sacc[r];
}

// ---------------- top-512 per row (stable ties) --------------------------
__global__ __launch_bounds__(256) void k_topk(const float* __restrict__ score,
                                              int* __restrict__ tki, int* __restrict__ tkc) {
    int t = blockIdx.x;
    int n = t + 1;
    int tid = threadIdx.x;
    if (n <= TOPK_N) {
        for (int i = tid; i < n; i += 256) tki[(size_t)t * TOPK_N + i] = i;
        if (tid == 0) tkc[t] = n;
        return;
    }
    __shared__ unsigned keys[2048];
    const float* row = score + (size_t)t * T_N;
    for (int i = tid; i < n; i += 256) {
        float f = row[i] + 0.f;
        unsigned u = __float_as_uint(f);
        u = (u & 0x80000000u) ? ~u : (u | 0x80000000u);
        keys[i] = u;
    }
    __shared__ int hist[256];
    __shared__ unsigned sh_prefix;
    __shared__ int sh_need;
    if (tid == 0) { sh_prefix = 0u; sh_need = TOPK_N; }
    __syncthreads();
    unsigned maskHi = 0;
    for (int level = 3; level >= 0; --level) {
        hist[tid] = 0;
        __syncthreads();
        unsigned prefix = sh_prefix;
        int shift = level * 8;
        for (int i = tid; i < n; i += 256) {
            unsigned kk = keys[i];
            if ((kk & maskHi) == prefix) atomicAdd(&hist[(kk >> shift) & 255], 1);
        }
        __syncthreads();
        if (tid == 0) {
            int need = sh_need, cum = 0, bsel = 255;
            for (int bb = 255; bb >= 0; --bb) {
                if (cum + hist[bb] >= need) { bsel = bb; break; }
                cum += hist[bb];
            }
            sh_need = need - cum;
            sh_prefix = prefix | ((unsigned)bsel << shift);
        }
        __syncthreads();
        maskHi |= (0xFFu << shift);
    }
    unsigned thr = sh_prefix;
    int needEq = sh_need;
    int base = tid * 8;
    int eqcnt = 0;
#pragma unroll
    for (int j = 0; j < 8; ++j) {
        int i = base + j;
        if (i < n && keys[i] == thr) eqcnt++;
    }
    __shared__ int scn[256];
    scn[tid] = eqcnt;
    __syncthreads();
    for (int off = 1; off < 256; off <<= 1) {
        int add = (tid >= off) ? scn[tid - off] : 0;
        __syncthreads();
        scn[tid] += add;
        __syncthreads();
    }
    int eq_excl = scn[tid] - eqcnt;
    int acnt = 0;
    {
        int eqr = eq_excl;
#pragma unroll
        for (int j = 0; j < 8; ++j) {
            int i = base + j;
            if (i < n) {
                unsigned kk = keys[i];
                bool a = (kk > thr) || (kk == thr && eqr < needEq);
                if (kk == thr) eqr++;
                if (a) acnt++;
            }
        }
    }
    __syncthreads();
    scn[tid] = acnt;
    __syncthreads();
    for (int off = 1; off < 256; off <<= 1) {
        int add = (tid >= off) ? scn[tid - off] : 0;
        __syncthreads();
        scn[tid] += add;
        __syncthreads();
    }
    int pos = scn[tid] - acnt;
    {
        int eqr = eq_excl;
#pragma unroll
        for (int j = 0; j < 8; ++j) {
            int i = base + j;
            if (i < n) {
                unsigned kk = keys[i];
                bool a = (kk > thr) || (kk == thr && eqr < needEq);
                if (kk == thr) eqr++;
                if (a) tki[(size_t)t * TOPK_N + (pos++)] = i;
            }
        }
    }
    if (tid == 0) tkc[t] = TOPK_N;
}

// ======== fused sparse MFMA attention, single-pass flash-style (r13 body + setprio) =====
__global__ __launch_bounds__(256, 2) void k_attn_mfma(const ushortT* __restrict__ qcat,
                                                      const ushortT* __restrict__ kcat,
                                                      const int* __restrict__ tki,
                                                      const int* __restrict__ tkc,
                                                      ushortT* __restrict__ olat) {
    int t = blockIdx.x;
    int tid = threadIdx.x;
    int lane = tid & 63;
    int w = tid >> 6;                 // 4 waves
    int S = tkc[t];
    int nchunk = (S + 31) >> 5;

    __shared__ int idx_s[512];
    __shared__ __align__(16) ushortT kbK[18 * 1024];  // [kk][32 keys][32 dims] 36864B
    __shared__ __align__(16) ushortT kbV[512 * 32];   // [512 dims][32 keys, grp-rotated]
    __shared__ __align__(16) ushortT psc[32 * 32];    // [32 heads][32 keys]     2048B
    __shared__ float red[64];                         // [head][nt] partial sums

    idx_s[tid] = (tid < S) ? tki[(size_t)t * TOPK_N + tid] : 0;
    idx_s[tid + 256] = (tid + 256 < S) ? tki[(size_t)t * TOPK_N + tid + 256] : 0;

    int lr = lane & 15, lk = lane >> 4;
    int mt = w >> 1, nt = w & 1;      // score quadrant: heads mt*16, keys nt*16

    bf16x8 qf[18];
    {
        const ushortT* qrow = qcat + (size_t)t * 18432 + (size_t)(mt * 16 + lr) * 576 + lk * 8;
#pragma unroll
        for (int kk = 0; kk < 18; ++kk) qf[kk] = *(const bf16x8*)(qrow + kk * 32);
    }
    __syncthreads();

    // coalesced staging map: 8 lanes cover 128 consecutive bytes of one key row
    int skey = (w << 3) | (lane >> 3);   // 0..31
    int part = lane & 7;                 // 16B chunk index within each 128B group

    f32x4 oa[2][8];
#pragma unroll
    for (int i = 0; i < 2; ++i)
#pragma unroll
        for (int j = 0; j < 8; ++j) oa[i][j] = (f32x4){0.f, 0.f, 0.f, 0.f};
    float sm_[4] = {0.f, 0.f, 0.f, 0.f};

    uint4 sv[9];
    {   // prefetch chunk 0
        bool ok = skey < S;
        const ushortT* g = kcat + (size_t)idx_s[skey] * 576 + part * 8;
#pragma unroll
        for (int i = 0; i < 9; ++i) {
            uint4 v = {0, 0, 0, 0};
            if (ok) v = *(const uint4*)(g + i * 64);
            sv[i] = v;
        }
    }

    for (int p = 0; p < nchunk; ++p) {
        // ---- stage chunk p: K-layout + V-transposed (grp-rotated) ----
#pragma unroll
        for (int i = 0; i < 9; ++i) {
            int dg = part + i * 8;
            int off = ((skey * 64 + (dg & 3) * 16) ^ ((skey & 7) << 4)) + (dg >> 2) * 2048;
            *(uint4*)((char*)kbK + off) = sv[i];
        }
#pragma unroll
        for (int i = 0; i < 8; ++i) {           // dg < 64: V dims only
            int dg = part + i * 8;
            int inner = ((((skey >> 3) + (dg & 3)) & 3) << 4) | ((skey & 7) << 1);
            const ushortT* pv = (const ushortT*)&sv[i];
#pragma unroll
            for (int j = 0; j < 8; ++j) {       // dim = dg*8+j, dim&7 == j
                int off = ((dg * 8 + j) * 64 + inner) ^ (j << 4);
                *(ushortT*)((char*)kbV + off) = pv[j];
            }
        }
        __syncthreads();
        // issue prefetch AFTER the barrier: latency hides under score MFMA + exp
        if (p + 1 < nchunk) {
            int gk = (p + 1) * 32 + skey;
            bool ok = gk < S;
            const ushortT* g = kcat + (size_t)idx_s[gk] * 576 + part * 8;
#pragma unroll
            for (int i = 0; i < 9; ++i) {
                uint4 v = {0, 0, 0, 0};
                if (ok) v = *(const uint4*)(g + i * 64);
                sv[i] = v;
            }
        }
        // ---- score: C[16h][16k] for quadrant (mt, nt) ----
        f32x4 acc = (f32x4){0.f, 0.f, 0.f, 0.f};
        int brow = nt * 16 + lr;
        __builtin_amdgcn_s_setprio(1);
#pragma unroll
        for (int kk = 0; kk < 18; ++kk) {
            bf16x8 b = *(const bf16x8*)((const char*)kbK + kk * 2048 +
                        ((brow * 64 + lk * 16) ^ ((brow & 7) << 4)));
            acc = __builtin_amdgcn_mfma_f32_16x16x32_bf16(qf[kk], b, acc, 0, 0, 0);
        }
        __builtin_amdgcn_s_setprio(0);
        // ---- exp (m=0), accumulate sums, write P chunk ----
        int key_g = p * 32 + nt * 16 + lr;
        int hb = mt * 16 + lk * 4;
#pragma unroll
        for (int r = 0; r < 4; ++r) {
            float e = (key_g < S) ? expf(acc[r]) : 0.f;
            sm_[r] += e;
            int head = hb + r;
            int off = (head * 64 + (nt * 16 + lr) * 2) ^ ((head & 7) << 4);
            *(ushortT*)((char*)psc + off) = f2bf(e);
        }
        __syncthreads();
        // ---- PV: all 32 heads x this wave's 128 dims, K = 32 chunk keys ----
        __builtin_amdgcn_s_setprio(1);
#pragma unroll
        for (int m2 = 0; m2 < 2; ++m2) {
            int arow = m2 * 16 + lr;
            bf16x8 a = *(const bf16x8*)((const char*)psc +
                        ((arow * 64 + lk * 16) ^ ((arow & 7) << 4)));
#pragma unroll
            for (int n2 = 0; n2 < 8; ++n2) {
                int dim = w * 128 + n2 * 16 + lr;
                int grp = (lk + ((dim >> 3) & 3)) & 3;
                bf16x8 b = *(const bf16x8*)((const char*)kbV +
                            ((dim * 64 + (grp << 4)) ^ ((dim & 7) << 4)));
                oa[m2][n2] = __builtin_amdgcn_mfma_f32_16x16x32_bf16(a, b, oa[m2][n2], 0, 0, 0);
            }
        }
        __builtin_amdgcn_s_setprio(0);
        __syncthreads();
    }
    // ---- reduce per-head sums: over lr lanes, then across nt waves via LDS ----
#pragma unroll
    for (int off = 1; off < 16; off <<= 1)
#pragma unroll
        for (int r = 0; r < 4; ++r) sm_[r] += __shfl_xor(sm_[r], off);
    if (lr == 0) {
#pragma unroll
        for (int r = 0; r < 4; ++r) red[(mt * 16 + lk * 4 + r) * 2 + nt] = sm_[r];
    }
    __syncthreads();
    // ---- normalize, stage [32 heads][512 dims] bf16 into kbK (swizzled) ----
#pragma unroll
    for (int m2 = 0; m2 < 2; ++m2)
#pragma unroll
        for (int r = 0; r < 4; ++r) {
            int head = m2 * 16 + lk * 4 + r;
            float dvv = 1.f / (red[head * 2] + red[head * 2 + 1]);
#pragma unroll
            for (int n2 = 0; n2 < 8; ++n2) {
                int dim = w * 128 + n2 * 16 + lr;
                int off = (head * 1024 + dim * 2) ^ ((head & 7) << 4);
                *(ushortT*)((char*)kbK + off) = f2bf(oa[m2][n2][r] * dvv);
            }
        }
    __syncthreads();
    // ---- coalesced store: 4 consecutive lanes cover 64B of one head row ----
    ushortT* orow = olat + (size_t)t * 18432;
#pragma unroll
    for (int i = 0; i < 8; ++i) {
        int idx = i * 256 + tid;
        int head = idx >> 6, seg = idx & 63;
        uint4 v = *(const uint4*)((const char*)kbK +
                   ((head * 1024 + seg * 16) ^ ((head & 7) << 4)));
        *(uint4*)(orow + head * 512 + seg * 8) = v;
    }
}

// ---------------- launch ----------------
extern "C" void kernel_launch(void* const* d_in, const int* in_sizes, int n_in,
                              void* d_out, int out_size, void* d_ws, size_t ws_size,
                              hipStream_t stream) {
    (void)in_sizes; (void)n_in; (void)out_size; (void)ws_size;
    const int*   positions = (const int*)d_in[0];
    const float* hs        = (const float*)d_in[1];
    const float* q_c       = (const float*)d_in[2];
    const float* kv_lora   = (const float*)d_in[3];
    const float* W_qb      = (const float*)d_in[4];
    const float* W_kvb     = (const float*)d_in[5];
    const float* W_o       = (const float*)d_in[6];
    const float* kv_ln     = (const float*)d_in[7];
    const float* W_iq      = (const float*)d_in[8];
    const float* W_ik      = (const float*)d_in[9];
    const float* gamma     = (const float*)d_in[10];
    const float* beta      = (const float*)d_in[11];
    const float* W_iw      = (const float*)d_in[12];

    float* ws = (float*)d_ws;
    // workspace (float offsets); high-water 50,204,672 fl = 200.8 MB (< 218.4 proven)
    float*   cosT   = ws;                          // 65,536
    float*   sinT   = ws + 65536;                  // 65,536
    int*     tki    = (int*)(ws + 131072);         // 1,048,576
    int*     tkc    = (int*)(ws + 1179648);        // 2,048
    ushortT* kcat   = (ushortT*)(ws + 1181696);    // 589,824 fl
    float*   kscale = ws + 1771520;                // 2,048
    float*   qscale = ws + 1773568;                // 65,536
    float*   wts    = ws + 1839104;                // 65,536
    uchar*   qi8    = (uchar*)(ws + 1904640);      // 2,097,152 fl (8 MB bytes)
    uchar*   ki8    = (uchar*)(ws + 4001792);      // 65,536 fl
    // qc_bf persistent through step 11:
    ushortT* qc_bf  = (ushortT*)(ws + 4067328);    // 1,572,864 fl [2a -> read 4, 11]
    // REGION R1 5,640,192..20,844,544, time-multiplexed:
    ushortT* wiq_t  = (ushortT*)(ws + 5640192);    // 3,145,728 fl [2b -> dead after 4]
    float*   kip    = ws + 8785920;                // 4,194,304  [2 -> dead after 3]
    ushortT* qi_bf  = (ushortT*)(ws + 12980224);   // 4,194,304 fl [4 -> dead after 5]
    ushortT* wqb_t  = (ushortT*)(ws + 5640192);    // 4,718,592 fl [10, over wiq_t/kip]
    ushortT* wuk_t  = (ushortT*)(ws + 10358784);   // 1,048,576 fl [10 -> dead after 13]
    ushortT* wuv_t  = (ushortT*)(ws + 11407360);   // 1,048,576 fl [10 -> read at 15]
    ushortT* wo_t   = (ushortT*)(ws + 12980224);   // 4,194,304 fl [10, over qi_bf]
    // score / vbuf slot:
    float*   score  = ws + 20844544;               // 4,194,304 [7 -> dead after 8]
    ushortT* vbuf   = (ushortT*)(ws + 20844544);   // 4,194,304 fl [15 -> 16]
    // persistent tail:
    ushortT* qfull_bf = (ushortT*)(ws + 25038848); // 6,291,456 fl [11 -> 12,13]
    ushortT* qcat   = (ushortT*)(ws + 31330304);   // 18,874,368 fl; o written in place (14)

    // 1. rope tables
    k_rope_tables<<<T_N, 32, 0, stream>>>(positions, cosT, sinT);
    // 2a/2b. bf16 casts for the q-path GEMMs
    k_cast4<<<3072, 256, 0, stream>>>(q_c, qc_bf, T_N * QLORA_N / 4);
    k_tcast<<<dim3(48, 128, 1), 256, 0, stream>>>(W_iq, wiq_t, 4096, 0, 0, 1536, 0);
    // 2. indexer k: hs @ W_ik (2048x128x2048), split-K x16 -> partials (f32, exact)
    gemm128<false><<<dim3(1, 16, 16), 256, 0, stream>>>(
        hs, W_ik, kip, T_N, 128, 128, HID_N, 128, 128, 128, 16384, 262144);
    // 3. sum partials + LN + neox rope + fp8 quant -> ki8 bytes
    k_ki_post16<<<T_N, 128, 0, stream>>>(kip, gamma, beta, cosT, sinT, ki8, kscale);
    // 4. indexer q: qc_bf @ wiq_t (bf16 MFMA) -> qi_bf (2048x4096)
    bgemm<true><<<dim3(32, 16, 1), 256, 0, stream>>>(
        qc_bf, wiq_t, qi_bf, QLORA_N, QLORA_N, QLORA_N, 4096, 0, 0, 0, 1.f);
    // 5. neox rope + fp8 quant -> qi8 bytes
    k_qi_post_bf<<<T_N * IDX_H_N, 128, 0, stream>>>(qi_bf, cosT, sinT, qi8, qscale);
    // 6. indexer weights
    k_wiw<<<T_N, 256, 0, stream>>>(hs, W_iw, qscale, wts);
    // 7. indexer score via fp8 MFMA
    k_score8<<<2080, 256, 0, stream>>>(qi8, ki8, kscale, wts, score);
    // 8. top-512
    k_topk<<<T_N, 256, 0, stream>>>(score, tki, tkc);
    // 9. kv rms_norm + k_pe rope -> kcat bf16
    k_kv_post2<<<T_N, 256, 0, stream>>>(kv_lora, kv_ln, cosT, sinT, kcat);
    // 10. remaining weight transposes (R1 free again)
    k_tcast<<<dim3(48, 192, 1), 256, 0, stream>>>(W_qb, wqb_t, 6144, 0, 0, 1536, 0);
    k_wuk_cast<<<8192, 256, 0, stream>>>(W_kvb, wuk_t);
    k_tcast<<<dim3(16, 4, 32), 256, 0, stream>>>(W_kvb, wuv_t, 8192, 128, 256, 512, 65536);
    k_tcast<<<dim3(128, 64, 1), 256, 0, stream>>>(W_o, wo_t, 2048, 0, 0, 4096, 0);
    // 11. qfull = q_c @ W_qb (bf16 MFMA) -> bf16 (T,32,192)
    bgemm<true><<<dim3(48, 16, 1), 256, 0, stream>>>(
        qc_bf, wqb_t, qfull_bf, QLORA_N, QLORA_N, QLORA_N, 6144, 0, 0, 0, 1.f);
    // 12. rope q_pe -> qcat[...,512:576]
    k_rope_q2<<<T_N * H_N / 8, 256, 0, stream>>>(qfull_bf, cosT, sinT, qcat);
    // 13. q_lat = q_nope @ W_UK^T per head -> qcat[...,0:512] (SCALE folded)
    bgemm<true><<<dim3(4, 16, 32), 256, 0, stream>>>(
        qfull_bf, wuk_t, qcat, NOPE_N, 6144, 128, 18432, 192, 65536, 576, SCALE_F);
    // 14. fused sparse MFMA attention (single-pass) -> o written in place into qcat rows
    k_attn_mfma<<<T_N, 256, 0, stream>>>(qcat, kcat, tki, tkc, qcat);
    // 15. v = o @ W_UV per head -> vbuf bf16 (T,4096)
    bgemm<true><<<dim3(1, 16, 32), 256, 0, stream>>>(
        qcat, wuv_t, vbuf, KVLORA_N, 18432, 512, 4096, 512, 65536, 128, 1.f);
    // 16. out = vbuf @ W_o -> f32 (128x64 tile: 512 blocks = 2/CU instead of 1/CU)
    bgemm64<<<dim3(32, 16), 256, 0, stream>>>(
        vbuf, wo_t, (float*)d_out, H_N * VD_N, 4096, 4096, HID_N);
}